// Round 8
// baseline (944.463 us; speedup 1.0000x reference)
//
#include <hip/hip_runtime.h>
#include <hip/hip_bf16.h>

// FlowAttention: B=4 S=4096 D=1024 H=16 dk=dv=64. Inputs/outputs fp32.
// Round-13: per-batch occupancy fix. R7 settled the gemm structure (R3 body +
// XCD swizzle = 90.7us full-batch). Remaining gap (~380us vs ideal) is the
// per-batch kernels running 256-block grids (1 block/CU, no TLP to hide the
// 2-barrier vmcnt drain). This round:
//  - gemm64: 64x64-tile variant (4 waves of 32x32, BK=64, same swizzle/DMA
//    discipline, 24KB/16KB LDS) for the 8 per-batch GEMMs -> 1024 blocks (4/CU).
//  - kv_k split 16->32, ctx_k split 16->32 (512 blocks, 2/CU).
//  - full-batch gemm128, stats, ln, transposes: unchanged from R7 (proven).
// Numerics: identical K-accumulation order per output -> bit-identical.
// Phase order (race-audited, unchanged):
//   memset sums; P1: Q->dout[0,32), K->dout[32,64) (epilogue colsums); WV^T stays
//   stats: dots1_k, dots2(dots_k), softmax(in-place)
//   P2 per b: V_b->ws (gemm64 AF32); memset kvb; kv_k; ctx_b overwrites dead K_b
//   WF^T; P3 per b: O_b = ctx_b@Wfc -> ws slot (gemm64 bf16); LN -> dout fp32
#define S_LEN 4096
#define DMODEL 1024
#define NHEAD 16
#define NROWS 16384      // B*S
#define BROWS 4096       // rows per batch
#define KV_SPLIT 32

typedef __bf16 bf16x8 __attribute__((ext_vector_type(8)));
typedef float  f32x4  __attribute__((ext_vector_type(4)));

__device__ __forceinline__ float b2f(ushort u) {
    union { uint i; float f; } c; c.i = ((uint)u) << 16; return c.f;
}
__device__ __forceinline__ float blo(uint u) {
    union { uint i; float f; } c; c.i = u << 16; return c.f;
}
__device__ __forceinline__ float bhi(uint u) {
    union { uint i; float f; } c; c.i = u & 0xFFFF0000u; return c.f;
}
__device__ __forceinline__ ushort f2b(float f) {
    union { uint i; float f; } c; c.f = f;
    uint r = c.i + 0x7FFF + ((c.i >> 16) & 1);   // round-to-nearest-even
    return (ushort)(r >> 16);
}
__device__ __forceinline__ float sigmoidf_(float x) {
    return 1.f / (1.f + __expf(-x));
}

// async 16B global->LDS DMA. Dest must be thread-linear (base + tid*16).
__device__ __forceinline__ void gld_lds16(void* lds, const void* g) {
    __builtin_amdgcn_global_load_lds(
        (const __attribute__((address_space(1))) uint*)g,
        (__attribute__((address_space(3))) uint*)lds, 16, 0, 0);
}

// ---------------- transpose 1024x1024: out[n][k] = bf16(in[k][n]), in fp32 ------
__global__ void transpose_k(const float* __restrict__ in, ushort* __restrict__ out) {
    __shared__ ushort tile[32][33];
    int x = blockIdx.x * 32 + threadIdx.x;
    int y0 = blockIdx.y * 32;
    for (int i = threadIdx.y; i < 32; i += 8)
        tile[i][threadIdx.x] = f2b(in[(size_t)(y0 + i) * DMODEL + x]);
    __syncthreads();
    int xo = blockIdx.y * 32 + threadIdx.x;
    int yo0 = blockIdx.x * 32;
    for (int i = threadIdx.y; i < 32; i += 8)
        out[(size_t)(yo0 + i) * DMODEL + xo] = tile[threadIdx.x][i];
}

// ---------------- MFMA GEMM 128x128 (full-batch): R7 body, unchanged ------------
template<int AF32>
__global__ __launch_bounds__(256) void gemm128(const void* __restrict__ A, size_t aoff,
                                               const ushort* __restrict__ Bt,
                                               ushort* __restrict__ C, int act,
                                               float* __restrict__ csum) {
    constexpr int SMEM_BYTES = AF32 ? 49152 : 32768;
    __shared__ __align__(16) char smem[SMEM_BYTES];
    char* smA = smem + 16384;

    int nwg = (int)(gridDim.x * gridDim.y);
    int bid = (int)(blockIdx.y * gridDim.x + blockIdx.x);
    int lid = (bid & 7) * (nwg >> 3) + (bid >> 3);
    int n0 = (lid & 7) * 128;                     // gridDim.x == 8
    int m0 = (lid >> 3) * 128;

    int t = threadIdx.x;
    int lane = t & 63, wave = t >> 6;
    int wm = (wave >> 1) * 64, wn = (wave & 1) * 64;
    int fr = lane & 15;            // frag row (A) / col (B)
    int kq = (lane >> 4) * 8;      // k offset within 32-step

    const float*  Af = (const float*)A + aoff;
    const ushort* Ab = (const ushort*)A + aoff;

    int ldsOff[4], rowOf[4], bcB[4];
    #pragma unroll
    for (int r = 0; r < 4; ++r) {
        int o = t * 16 + r * 4096;
        int row = o >> 7;
        ldsOff[r] = o;
        rowOf[r] = row;
        bcB[r] = (o & 127) ^ ((row & 7) << 4);
    }

    f32x4 acc[4][4];
    #pragma unroll
    for (int i = 0; i < 4; ++i)
        #pragma unroll
        for (int j = 0; j < 4; ++j) acc[i][j] = (f32x4){0.f, 0.f, 0.f, 0.f};

    for (int k0 = 0; k0 < DMODEL; k0 += 64) {
        __syncthreads();
        #pragma unroll
        for (int r = 0; r < 4; ++r)
            gld_lds16(smem + ldsOff[r],
                      Bt + (size_t)(n0 + rowOf[r]) * DMODEL + k0 + (bcB[r] >> 1));
        if (AF32) {
            #pragma unroll
            for (int hh = 0; hh < 2; ++hh)
                #pragma unroll
                for (int r = 0; r < 4; ++r)
                    gld_lds16(smA + hh * 16384 + ldsOff[r],
                              Af + (size_t)(m0 + rowOf[r]) * DMODEL + k0 + hh * 32 + (bcB[r] >> 2));
        } else {
            #pragma unroll
            for (int r = 0; r < 4; ++r)
                gld_lds16(smA + ldsOff[r],
                          Ab + (size_t)(m0 + rowOf[r]) * DMODEL + k0 + (bcB[r] >> 1));
        }
        __syncthreads();

        #pragma unroll
        for (int h = 0; h < 2; ++h) {
            bf16x8 av[4], bv[4];
            #pragma unroll
            for (int i = 0; i < 4; ++i) {
                int row = wm + i * 16 + fr;
                int swz = (row & 7) << 4;
                if (AF32) {
                    const char* Ah = smA + h * 16384;
                    int o1 = ((row << 7) + (kq << 2)) ^ swz;
                    int o2 = ((row << 7) + ((kq + 4) << 2)) ^ swz;
                    float4 q0 = *(const float4*)(Ah + o1);
                    float4 q1 = *(const float4*)(Ah + o2);
                    bf16x8 a;
                    a[0] = (__bf16)q0.x; a[1] = (__bf16)q0.y;
                    a[2] = (__bf16)q0.z; a[3] = (__bf16)q0.w;
                    a[4] = (__bf16)q1.x; a[5] = (__bf16)q1.y;
                    a[6] = (__bf16)q1.z; a[7] = (__bf16)q1.w;
                    av[i] = a;
                } else {
                    int k = h * 32 + kq;
                    int o = ((row << 7) + (k << 1)) ^ swz;
                    av[i] = *(const bf16x8*)(smA + o);
                }
            }
            #pragma unroll
            for (int j = 0; j < 4; ++j) {
                int nrow = wn + j * 16 + fr;
                int k = h * 32 + kq;
                int o = ((nrow << 7) + (k << 1)) ^ ((nrow & 7) << 4);
                bv[j] = *(const bf16x8*)(smem + o);
            }
            #pragma unroll
            for (int i = 0; i < 4; ++i)
                #pragma unroll
                for (int j = 0; j < 4; ++j)
                    acc[i][j] = __builtin_amdgcn_mfma_f32_16x16x32_bf16(av[i], bv[j], acc[i][j], 0, 0, 0);
        }
    }

    int rbase = (lane >> 4) * 4;
    int cix = lane & 15;
    float colacc[4] = {0.f, 0.f, 0.f, 0.f};
    #pragma unroll
    for (int i = 0; i < 4; ++i)
        #pragma unroll
        for (int j = 0; j < 4; ++j) {
            int col = n0 + wn + j * 16 + cix;
            #pragma unroll
            for (int r = 0; r < 4; ++r) {
                int row = m0 + wm + i * 16 + rbase + r;
                float v = acc[i][j][r];
                if (act) v = sigmoidf_(v);
                ushort ub = f2b(v);
                C[(size_t)row * DMODEL + col] = ub;
                if (csum) colacc[j] += b2f(ub);
            }
        }
    if (csum) {
        __syncthreads();
        float* cred = (float*)smem;     // [2][128]
        cred[t] = 0.f;
        __syncthreads();
        #pragma unroll
        for (int j = 0; j < 4; ++j) {
            float s = colacc[j];
            s += __shfl_xor(s, 16);
            s += __shfl_xor(s, 32);
            if (lane < 16) cred[(wm >> 6) * 128 + wn + j * 16 + lane] = s;
        }
        __syncthreads();
        if (t < 128) {
            float tot = cred[t] + cred[128 + t];
            int col = n0 + t;
            int b = m0 >> 12;
            atomicAdd(&csum[((size_t)b * NHEAD + (col >> 6)) * 64 + (col & 63)], tot);
        }
    }
}

// ---------------- MFMA GEMM 64x64 (per-batch, occupancy-first) ------------------
// 4 waves 2x2, each wave 32x32 via 2x2 mfma 16x16x32 bf16, BK=64.
// LDS: B bf16 [64][64] @0 (8KB); A: AF32 ? f32 [64][64] @8K (16KB, 256B rows)
//      : bf16 [64][64] @8K (8KB). Totals 24KB / 16KB -> 4+ blocks/CU at
//      grid (16,64)=1024 blocks. Same swizzle discipline as gemm128.
// XCD swizzle: lid=(bid&7)*(nwg/8)+bid/8; n0=(lid&15)*64, m0=(lid>>4)*64.
template<int AF32>
__global__ __launch_bounds__(256) void gemm64(const void* __restrict__ A, size_t aoff,
                                              const ushort* __restrict__ Bt,
                                              ushort* __restrict__ C, int act) {
    constexpr int SMEM_BYTES = AF32 ? 24576 : 16384;
    __shared__ __align__(16) char smem[SMEM_BYTES];
    char* smA = smem + 8192;

    int nwg = (int)(gridDim.x * gridDim.y);                  // 1024
    int bid = (int)(blockIdx.y * gridDim.x + blockIdx.x);
    int lid = (bid & 7) * (nwg >> 3) + (bid >> 3);
    int n0 = (lid & 15) * 64;                                // gridDim.x == 16
    int m0 = (lid >> 4) * 64;

    int t = threadIdx.x;
    int lane = t & 63, wave = t >> 6;
    int wm = (wave >> 1) * 32, wn = (wave & 1) * 32;
    int fr = lane & 15;
    int kq = (lane >> 4) * 8;

    const float*  Af = (const float*)A + aoff;
    const ushort* Ab = (const ushort*)A + aoff;

    f32x4 acc[2][2];
    #pragma unroll
    for (int i = 0; i < 2; ++i)
        #pragma unroll
        for (int j = 0; j < 2; ++j) acc[i][j] = (f32x4){0.f, 0.f, 0.f, 0.f};

    for (int k0 = 0; k0 < DMODEL; k0 += 64) {
        __syncthreads();
        // B tile [64][64] bf16, 8KB: 2 DMA rounds (128B rows)
        #pragma unroll
        for (int r = 0; r < 2; ++r) {
            int o = t * 16 + r * 4096;
            int row = o >> 7;
            int cb = (o & 127) ^ ((row & 7) << 4);
            gld_lds16(smem + o, Bt + (size_t)(n0 + row) * DMODEL + k0 + (cb >> 1));
        }
        if (AF32) {
            // A tile [64][64] f32, 16KB: 4 DMA rounds (256B rows)
            #pragma unroll
            for (int r = 0; r < 4; ++r) {
                int o = t * 16 + r * 4096;
                int row = o >> 8;
                int cb = (o & 255) ^ ((row & 7) << 4);
                gld_lds16(smA + o, Af + (size_t)(m0 + row) * DMODEL + k0 + (cb >> 2));
            }
        } else {
            #pragma unroll
            for (int r = 0; r < 2; ++r) {
                int o = t * 16 + r * 4096;
                int row = o >> 7;
                int cb = (o & 127) ^ ((row & 7) << 4);
                gld_lds16(smA + o, Ab + (size_t)(m0 + row) * DMODEL + k0 + (cb >> 1));
            }
        }
        __syncthreads();   // vmcnt(0) drain

        #pragma unroll
        for (int h = 0; h < 2; ++h) {
            bf16x8 av[2], bv[2];
            #pragma unroll
            for (int i = 0; i < 2; ++i) {
                int row = wm + i * 16 + fr;
                int swz = (row & 7) << 4;
                if (AF32) {
                    int k = h * 32 + kq;
                    int o1 = ((row << 8) + (k << 2)) ^ swz;
                    int o2 = ((row << 8) + ((k + 4) << 2)) ^ swz;
                    float4 q0 = *(const float4*)(smA + o1);
                    float4 q1 = *(const float4*)(smA + o2);
                    bf16x8 a;
                    a[0] = (__bf16)q0.x; a[1] = (__bf16)q0.y;
                    a[2] = (__bf16)q0.z; a[3] = (__bf16)q0.w;
                    a[4] = (__bf16)q1.x; a[5] = (__bf16)q1.y;
                    a[6] = (__bf16)q1.z; a[7] = (__bf16)q1.w;
                    av[i] = a;
                } else {
                    int k = h * 32 + kq;
                    int o = ((row << 7) + (k << 1)) ^ swz;
                    av[i] = *(const bf16x8*)(smA + o);
                }
            }
            #pragma unroll
            for (int j = 0; j < 2; ++j) {
                int nrow = wn + j * 16 + fr;
                int k = h * 32 + kq;
                int o = ((nrow << 7) + (k << 1)) ^ ((nrow & 7) << 4);
                bv[j] = *(const bf16x8*)(smem + o);
            }
            #pragma unroll
            for (int i = 0; i < 2; ++i)
                #pragma unroll
                for (int j = 0; j < 2; ++j)
                    acc[i][j] = __builtin_amdgcn_mfma_f32_16x16x32_bf16(av[i], bv[j], acc[i][j], 0, 0, 0);
        }
    }

    int rbase = (lane >> 4) * 4;
    int cix = lane & 15;
    #pragma unroll
    for (int i = 0; i < 2; ++i)
        #pragma unroll
        for (int j = 0; j < 2; ++j) {
            int col = n0 + wn + j * 16 + cix;
            #pragma unroll
            for (int r = 0; r < 4; ++r) {
                int row = m0 + wm + i * 16 + rbase + r;
                float v = acc[i][j][r];
                if (act) v = sigmoidf_(v);
                C[(size_t)row * DMODEL + col] = f2b(v);
            }
        }
}

// ---- fused dots1 + weighted colsum2, batched over b (z) ----
__global__ void dots1_k(const ushort* __restrict__ Q, const ushort* __restrict__ K,
                        const float* __restrict__ Qsum, const float* __restrict__ Ksum,
                        float* __restrict__ si_out, float* __restrict__ qsi,
                        float* __restrict__ kso) {
    int h = blockIdx.x, b = blockIdx.z;
    int lane = threadIdx.x & 63, wv = threadIdx.x >> 6;
    const ushort* qp = Q + (size_t)b * BROWS * DMODEL + h * 64 + lane;
    const ushort* kp = K + (size_t)b * BROWS * DMODEL + h * 64 + lane;
    float vql = Ksum[((size_t)b * NHEAD + h) * 64 + lane];
    float vkl = Qsum[((size_t)b * NHEAD + h) * 64 + lane];
    float* sip = si_out + ((size_t)b * NHEAD + h) * S_LEN;
    int s0 = blockIdx.y * 128 + wv * 32;
    float aq = 0.f, ak = 0.f;
    for (int i = 0; i < 32; ++i) {
        int s = s0 + i;
        float qv = b2f(qp[(size_t)s * DMODEL]);
        float kv = b2f(kp[(size_t)s * DMODEL]);
        float dq = qv * vql, dk = kv * vkl;
        #pragma unroll
        for (int off = 32; off; off >>= 1) {
            dq += __shfl_xor(dq, off);
            dk += __shfl_xor(dk, off);
        }
        float si_ = 1.f / dq, so_ = 1.f / dk;
        if (lane == 0) sip[s] = si_;
        aq += qv * si_;
        ak += kv * so_;
    }
    atomicAdd(&qsi[((size_t)b * NHEAD + h) * 64 + lane], aq);
    atomicAdd(&kso[((size_t)b * NHEAD + h) * 64 + lane], ak);
}

// ---- per-s dots with a per-head 64-vector, batched over b (z) ----
__global__ void dots_k(const ushort* __restrict__ Q, const ushort* __restrict__ K,
                       const float* __restrict__ vq, const float* __restrict__ vk,
                       float* __restrict__ outq, float* __restrict__ outk, int invert) {
    int h = blockIdx.x;
    int b = blockIdx.z;
    const ushort* Qb = Q + (size_t)b * BROWS * DMODEL;
    const ushort* Kb = K + (size_t)b * BROWS * DMODEL;
    const float* vqb = vq + (size_t)b * NHEAD * 64;
    const float* vkb = vk + (size_t)b * NHEAD * 64;
    float* oq = outq + (size_t)b * NHEAD * S_LEN;
    float* ok = outk + (size_t)b * NHEAD * S_LEN;
    int lane = threadIdx.x & 63, wv = threadIdx.x >> 6;
    const ushort* qp = Qb + h * 64 + lane;
    const ushort* kp = Kb + h * 64 + lane;
    float vql = vqb[h * 64 + lane];
    float vkl = vkb[h * 64 + lane];
    int s0 = blockIdx.y * 128 + wv * 32;
    for (int i = 0; i < 32; ++i) {
        int s = s0 + i;
        float dq = b2f(qp[(size_t)s * DMODEL]) * vql;
        float dk = b2f(kp[(size_t)s * DMODEL]) * vkl;
        #pragma unroll
        for (int off = 32; off; off >>= 1) {
            dq += __shfl_xor(dq, off);
            dk += __shfl_xor(dk, off);
        }
        if (lane == 0) {
            oq[(size_t)h * S_LEN + s] = invert ? 1.f / dq : dq;
            ok[(size_t)h * S_LEN + s] = invert ? 1.f / dk : dk;
        }
    }
}

// ---- softmax over S per head, batched over b (y); safe in-place (w may == x) ----
__global__ void softmax_k(const float* x, float* w) {
    int h = blockIdx.x;
    int b = blockIdx.y;
    const float* xp = x + ((size_t)b * NHEAD + h) * S_LEN;
    float* wp = w + ((size_t)b * NHEAD + h) * S_LEN;
    float loc[16];
    float mx = -1e30f;
    #pragma unroll
    for (int i = 0; i < 16; ++i) { loc[i] = xp[threadIdx.x + i * 256]; mx = fmaxf(mx, loc[i]); }
    __shared__ float red[256];
    red[threadIdx.x] = mx; __syncthreads();
    for (int st = 128; st; st >>= 1) {
        if (threadIdx.x < st) red[threadIdx.x] = fmaxf(red[threadIdx.x], red[threadIdx.x + st]);
        __syncthreads();
    }
    mx = red[0]; __syncthreads();
    float sm = 0.f;
    #pragma unroll
    for (int i = 0; i < 16; ++i) { loc[i] = __expf(loc[i] - mx); sm += loc[i]; }
    red[threadIdx.x] = sm; __syncthreads();
    for (int st = 128; st; st >>= 1) {
        if (threadIdx.x < st) red[threadIdx.x] += red[threadIdx.x + st];
        __syncthreads();
    }
    float inv = 1.f / red[0];
    #pragma unroll
    for (int i = 0; i < 16; ++i)
        wp[threadIdx.x + i * 256] = loc[i] * inv;
}

// ---- kv[h,k,v] = sum_s (K[s,k]*w[h,s]) * V[s,v], one batch (split-S atomics) ----
// Grid (16,32) = 512 blocks (2/CU). Bijective XCD remap; each block does 128 s.
__global__ __launch_bounds__(256) void kv_k(const ushort* __restrict__ K,
                                            const ushort* __restrict__ V,
                                            const float* __restrict__ w,
                                            float* __restrict__ kv) {
    int bid = (int)(blockIdx.y * gridDim.x + blockIdx.x);   // gridDim = (16, 32)
    int lid = (bid & 7) * 64 + (bid >> 3);                  // [0,512) bijective
    int h = lid & 15;
    int sy = lid >> 4;                                      // [0,32)
    __shared__ __align__(16) float  KwS[64 * 64];
    __shared__ __align__(16) ushort Vt[64 * 64];
    int t = threadIdx.x;
    int kk = (t & 31) * 2;
    int v0 = (t >> 5) * 8;
    float acc[2][8];
    #pragma unroll
    for (int i = 0; i < 2; ++i)
        #pragma unroll
        for (int j = 0; j < 8; ++j) acc[i][j] = 0.f;
    int sl_s = t >> 2, q = t & 3;
    int sBase = sy * (S_LEN / KV_SPLIT);                    // 128 rows per block
    for (int t0 = 0; t0 < S_LEN / KV_SPLIT; t0 += 64) {
        __syncthreads();
        #pragma unroll
        for (int r = 0; r < 2; ++r) {
            int o = t * 16 + r * 4096;
            int row = o >> 7;
            gld_lds16((char*)Vt + o,
                      V + (size_t)(sBase + t0 + row) * DMODEL + h * 64 + ((o & 127) >> 1));
        }
        {
            int s = sBase + t0 + sl_s;
            float ws = w[(size_t)h * S_LEN + s];
            const ushort* kp = K + (size_t)s * DMODEL + h * 64 + q * 16;
            uint4 ka = *(const uint4*)kp;
            uint4 kb = *(const uint4*)(kp + 8);
            int swz = (sl_s & 7) << 4;
            char* base = (char*)KwS + sl_s * 256;
            f32x4 c0 = { blo(ka.x) * ws, bhi(ka.x) * ws, blo(ka.y) * ws, bhi(ka.y) * ws };
            f32x4 c1 = { blo(ka.z) * ws, bhi(ka.z) * ws, blo(ka.w) * ws, bhi(ka.w) * ws };
            f32x4 c2 = { blo(kb.x) * ws, bhi(kb.x) * ws, blo(kb.y) * ws, bhi(kb.y) * ws };
            f32x4 c3 = { blo(kb.z) * ws, bhi(kb.z) * ws, blo(kb.w) * ws, bhi(kb.w) * ws };
            *(f32x4*)(base + ((q * 64 +  0) ^ swz)) = c0;
            *(f32x4*)(base + ((q * 64 + 16) ^ swz)) = c1;
            *(f32x4*)(base + ((q * 64 + 32) ^ swz)) = c2;
            *(f32x4*)(base + ((q * 64 + 48) ^ swz)) = c3;
        }
        __syncthreads();
        #pragma unroll 2
        for (int sl = 0; sl < 64; ++sl) {
            int swz = (sl & 7) << 4;
            float2 kf = *(const float2*)((const char*)KwS + sl * 256 + ((kk * 4) ^ swz));
            uint4 vv = *(const uint4*)((const char*)Vt + sl * 128 + v0 * 2);
            float vf0 = blo(vv.x), vf1 = bhi(vv.x), vf2 = blo(vv.y), vf3 = bhi(vv.y);
            float vf4 = blo(vv.z), vf5 = bhi(vv.z), vf6 = blo(vv.w), vf7 = bhi(vv.w);
            acc[0][0] += kf.x * vf0; acc[0][1] += kf.x * vf1;
            acc[0][2] += kf.x * vf2; acc[0][3] += kf.x * vf3;
            acc[0][4] += kf.x * vf4; acc[0][5] += kf.x * vf5;
            acc[0][6] += kf.x * vf6; acc[0][7] += kf.x * vf7;
            acc[1][0] += kf.y * vf0; acc[1][1] += kf.y * vf1;
            acc[1][2] += kf.y * vf2; acc[1][3] += kf.y * vf3;
            acc[1][4] += kf.y * vf4; acc[1][5] += kf.y * vf5;
            acc[1][6] += kf.y * vf6; acc[1][7] += kf.y * vf7;
        }
    }
    float* kvp = kv + (size_t)h * 4096;
    #pragma unroll
    for (int i = 0; i < 2; ++i)
        #pragma unroll
        for (int j = 0; j < 8; ++j)
            atomicAdd(&kvp[(kk + i) * 64 + v0 + j], acc[i][j]);
}

// ---- ctx[s,h*64+v] = sig(csink[h,s])*si[h,s]*sum_k Q[s,h*64+k]*kv[h,k,v] ----
// Grid (16,32) = 512 blocks (2/CU); each block does 128 s (2 tiles of 64).
__global__ __launch_bounds__(256) void ctx_k(const ushort* __restrict__ Q,
                                             const float* __restrict__ kv,
                                             const float* __restrict__ si,
                                             const float* __restrict__ csink,
                                             ushort* __restrict__ ctx) {
    int bid = (int)(blockIdx.y * gridDim.x + blockIdx.x);   // gridDim = (16, 32)
    int lid = (bid & 7) * 64 + (bid >> 3);                  // [0,512) bijective
    int h = lid & 15;
    int sBlock = (lid >> 4) * 128;
    __shared__ __align__(16) float  kvf[64 * 64];   // [k][v] linear
    __shared__ __align__(16) ushort Qt[64 * 64];    // [s][k] source-preswizzled
    int t = threadIdx.x;
    {
        const float* kp = kv + (size_t)h * 4096;
        #pragma unroll
        for (int i = 0; i < 4; ++i) {
            int idx = t * 4 + i * 1024;
            *(f32x4*)&kvf[idx] = *(const f32x4*)&kp[idx];
        }
    }
    int spair = t >> 3;
    int v0 = (t & 7) * 8;
    for (int tile = 0; tile < 2; ++tile) {
        __syncthreads();
        int sT = sBlock + tile * 64;
        #pragma unroll
        for (int r = 0; r < 2; ++r) {
            int o = t * 16 + r * 4096;
            int row = o >> 7;
            int cb = (o & 127) ^ ((row & 7) << 4);
            gld_lds16((char*)Qt + o, Q + (size_t)(sT + row) * DMODEL + h * 64 + (cb >> 1));
        }
        __syncthreads();
        int s0 = spair * 2, s1 = s0 + 1;
        int swz0 = (s0 & 7) << 4, swz1 = (s1 & 7) << 4;
        float acc0[8], acc1[8];
        #pragma unroll
        for (int j = 0; j < 8; ++j) { acc0[j] = 0.f; acc1[j] = 0.f; }
        #pragma unroll 4
        for (int k = 0; k < 64; k += 4) {
            union { ushort4 v; ushort u[4]; } qa, qb;
            qa.v = *(const ushort4*)((const char*)Qt + s0 * 128 + ((k * 2) ^ swz0));
            qb.v = *(const ushort4*)((const char*)Qt + s1 * 128 + ((k * 2) ^ swz1));
            const char* rbase = (const char*)kvf + k * 256 + v0 * 4;
            #pragma unroll
            for (int kk2 = 0; kk2 < 4; ++kk2) {
                f32x4 r0 = *(const f32x4*)(rbase + kk2 * 256);
                f32x4 r1 = *(const f32x4*)(rbase + kk2 * 256 + 16);
                float qaf = b2f(qa.u[kk2]);
                float qbf = b2f(qb.u[kk2]);
                #pragma unroll
                for (int j = 0; j < 4; ++j) {
                    acc0[j]     += qaf * r0[j];
                    acc0[4 + j] += qaf * r1[j];
                    acc1[j]     += qbf * r0[j];
                    acc1[4 + j] += qbf * r1[j];
                }
            }
        }
        int gs0 = sT + s0, gs1 = sT + s1;
        float sc0 = si[(size_t)h * S_LEN + gs0] * sigmoidf_(csink[(size_t)h * S_LEN + gs0]);
        float sc1 = si[(size_t)h * S_LEN + gs1] * sigmoidf_(csink[(size_t)h * S_LEN + gs1]);
        union { ushort u[8]; uint4 v; } o0, o1;
        #pragma unroll
        for (int j = 0; j < 8; ++j) {
            o0.u[j] = f2b(acc0[j] * sc0);
            o1.u[j] = f2b(acc1[j] * sc1);
        }
        *(uint4*)(ctx + (size_t)gs0 * DMODEL + h * 64 + v0) = o0.v;
        *(uint4*)(ctx + (size_t)gs1 * DMODEL + h * 64 + v0) = o1.v;
    }
}

// ---- LayerNorm(y_bf16 + residual_f32) * gamma + beta -> fp32 out (per-row) ----
__global__ void ln_k(const ushort* __restrict__ y, const float* __restrict__ res,
                     const float* __restrict__ gamma, const float* __restrict__ beta,
                     float* __restrict__ out) {
    size_t row = blockIdx.x;
    const ushort* yp = y + row * DMODEL;
    const float* rp = res + row * DMODEL;
    float x[4];
    float s = 0.f, s2 = 0.f;
    #pragma unroll
    for (int i = 0; i < 4; ++i) {
        int d = threadIdx.x + i * 256;
        x[i] = b2f(yp[d]) + rp[d];
        s += x[i]; s2 += x[i] * x[i];
    }
    __shared__ float r1[256], r2[256];
    r1[threadIdx.x] = s; r2[threadIdx.x] = s2;
    __syncthreads();
    for (int st = 128; st; st >>= 1) {
        if (threadIdx.x < st) { r1[threadIdx.x] += r1[threadIdx.x + st]; r2[threadIdx.x] += r2[threadIdx.x + st]; }
        __syncthreads();
    }
    float mean = r1[0] * (1.f / DMODEL);
    float var = r2[0] * (1.f / DMODEL) - mean * mean;
    float rstd = rsqrtf(var + 1e-5f);
    #pragma unroll
    for (int i = 0; i < 4; ++i) {
        int d = threadIdx.x + i * 256;
        out[row * DMODEL + d] = (x[i] - mean) * rstd * gamma[d] + beta[d];
    }
}

extern "C" void kernel_launch(void* const* d_in, const int* in_sizes, int n_in,
                              void* d_out, int out_size, void* d_ws, size_t ws_size,
                              hipStream_t stream) {
    const float* inQ  = (const float*)d_in[0];
    const float* inK  = (const float*)d_in[1];
    const float* inV  = (const float*)d_in[2];
    const float* WQ   = (const float*)d_in[3];
    const float* WK   = (const float*)d_in[4];
    const float* WV   = (const float*)d_in[5];
    const float* WF   = (const float*)d_in[6];
    const float* gamma= (const float*)d_in[7];
    const float* beta = (const float*)d_in[8];
    float* outf = (float*)d_out;

    // d_out scratch: bf16 Q at [0,32MB), bf16 K/ctx at [32,64MB)
    ushort* Qb  = (ushort*)d_out;
    ushort* KCb = (ushort*)d_out + (size_t)NROWS * DMODEL;

    // d_ws layout (peak 13.31MB < proven 13.6MB):
    const size_t MB = 1024ull * 1024ull;
    char* w = (char*)d_ws;
    ushort* Vb  = (ushort*)w;                 // [4096][1024] bf16, 8MB; later O_b slot
    ushort* Wt  = (ushort*)(w + 8 * MB);      // 2MB weight^T slot (WQ->WK->WV->WF)
    float* si    = (float*)(w + 10 * MB);     // [4][16][4096] f32, 1MB
    float* soCsk = si + 4 * NHEAD * S_LEN;    // 1MB: csk (dots2)
    float* css   = soCsk + 4 * NHEAD * S_LEN; // 1MB: css -> smw (softmax in-place)
    float* Qsum  = css + 4 * NHEAD * S_LEN;   // 4 sum buffers x [4][16][64] = 64KB
    float* Ksum  = Qsum + 4 * NHEAD * 64;
    float* QsI   = Ksum + 4 * NHEAD * 64;
    float* KsO   = QsI  + 4 * NHEAD * 64;
    float* kvb   = KsO  + 4 * NHEAD * 64;     // [16][64][64] f32, 256KB (per-batch)
    size_t sumZeroBytes = 4 * 4 * NHEAD * 64 * sizeof(float);   // 64KB
    size_t kvZeroBytes  = (size_t)NHEAD * 4096 * sizeof(float); // 256KB

    dim3 tb(32, 8);
    dim3 tg(32, 32);
    dim3 ggFull(DMODEL / 128, NROWS / 128);   // (8, 128)
    dim3 ggBat64(DMODEL / 64, BROWS / 64);    // (16, 64) = 1024 blocks

    // zero Qsum/Ksum/QsI/KsO before gemm epilogue atomics
    hipMemsetAsync(Qsum, 0, sumZeroBytes, stream);

    // Phase 1: Q and K projections (full batch) into d_out; epilogue colsums
    transpose_k<<<tg, tb, 0, stream>>>(WQ, Wt);
    gemm128<1><<<ggFull, 256, 0, stream>>>(inQ, 0, Wt, Qb, 1, Qsum);
    transpose_k<<<tg, tb, 0, stream>>>(WK, Wt);
    gemm128<1><<<ggFull, 256, 0, stream>>>(inK, 0, Wt, KCb, 1, Ksum);
    transpose_k<<<tg, tb, 0, stream>>>(WV, Wt);   // WVt stays through P2

    // Stats: fused dots1(+colsum2), dots2, softmax — all 4 batches per launch
    dots1_k<<<dim3(NHEAD, 32, 4), 256, 0, stream>>>(Qb, KCb, Qsum, Ksum, si, QsI, KsO);
    dots_k<<<dim3(NHEAD, 32, 4), 256, 0, stream>>>(Qb, KCb, KsO, QsI, soCsk, css, 0);
    softmax_k<<<dim3(NHEAD, 4), 256, 0, stream>>>(css, css);

    // Phase 2: per-batch V projection + kv + ctx (ctx_b overwrites dead K_b slice)
    for (int b = 0; b < 4; ++b) {
        size_t rowOff = (size_t)b * BROWS * DMODEL;
        size_t statOff = (size_t)b * NHEAD * S_LEN;
        const ushort* Qs = Qb + rowOff;
        ushort* Ks = KCb + rowOff;
        gemm64<1><<<ggBat64, 256, 0, stream>>>(inV, rowOff, Wt, Vb, 0);
        hipMemsetAsync(kvb, 0, kvZeroBytes, stream);
        kv_k<<<dim3(NHEAD, KV_SPLIT), 256, 0, stream>>>(Ks, Vb, css + statOff, kvb);
        ctx_k<<<dim3(NHEAD, 32), 256, 0, stream>>>(Qs, kvb, si + statOff, soCsk + statOff, Ks);
    }

    // Phase 3: output projection + LayerNorm (fp32 out)
    transpose_k<<<tg, tb, 0, stream>>>(WF, Wt);   // WVt dead now
    for (int b = 0; b < 4; ++b) {
        size_t rowOff = (size_t)b * BROWS * DMODEL;
        gemm64<0><<<ggBat64, 256, 0, stream>>>(KCb + rowOff, 0, Wt, Vb, 0);
        ln_k<<<BROWS, 256, 0, stream>>>(Vb, inQ + rowOff, gamma, beta, outf + rowOff);
    }
}

// Round 9
// 910.254 us; speedup vs baseline: 1.0376x; 1.0376x over previous
//
#include <hip/hip_runtime.h>
#include <hip/hip_bf16.h>

// FlowAttention: B=4 S=4096 D=1024 H=16 dk=dv=64. Inputs/outputs fp32.
// Round-14: launch-granularity restructure (stream is serial -> fewer, bigger
// launches; dependency interleave removed).
//  - kvb -> kvb[4] (per batch, +768KB; ws peak 14.06MB, +3% over proven 13.6).
//  - ctx_k batched over b (grid z=4, one 2048-block launch after all kv done).
//  - P3: ONE batched gemm64 launch (z=4): A=ctx_z (KCb+8z MB); C: z=0->Vb,
//    z>=1 -> Qb+(z-1)*8MB (Q dead after ctx). Then ln in order 3,2,1,0:
//      ln3 reads O3=Qb+16MB writes out[48,64) (ctx2/3 consumed)
//      ln2 reads O2=Qb+8MB  writes out[32,48) (ctx0/1 consumed)
//      ln1 reads O1=Qb+0    writes out[16,32) (O3 consumed)
//      ln0 reads O0=Vb      writes out[0,16)  (O1,O2 consumed)
//  - gemm128/gemm64 bodies, stats, kv_k inner loops: unchanged from R8 (R8's
//    gemm128 116us vs R7's 90.7 with identical code = clock/container noise;
//    non-gemm time improved 739->712, so R13's gemm64/splits kept).
#define S_LEN 4096
#define DMODEL 1024
#define NHEAD 16
#define NROWS 16384      // B*S
#define BROWS 4096       // rows per batch
#define KV_SPLIT 32
#define BATSTRIDE 4194304ull   // elements per batch slice (4096*1024)

typedef __bf16 bf16x8 __attribute__((ext_vector_type(8)));
typedef float  f32x4  __attribute__((ext_vector_type(4)));

__device__ __forceinline__ float b2f(ushort u) {
    union { uint i; float f; } c; c.i = ((uint)u) << 16; return c.f;
}
__device__ __forceinline__ float blo(uint u) {
    union { uint i; float f; } c; c.i = u << 16; return c.f;
}
__device__ __forceinline__ float bhi(uint u) {
    union { uint i; float f; } c; c.i = u & 0xFFFF0000u; return c.f;
}
__device__ __forceinline__ ushort f2b(float f) {
    union { uint i; float f; } c; c.f = f;
    uint r = c.i + 0x7FFF + ((c.i >> 16) & 1);   // round-to-nearest-even
    return (ushort)(r >> 16);
}
__device__ __forceinline__ float sigmoidf_(float x) {
    return 1.f / (1.f + __expf(-x));
}

// async 16B global->LDS DMA. Dest must be thread-linear (base + tid*16).
__device__ __forceinline__ void gld_lds16(void* lds, const void* g) {
    __builtin_amdgcn_global_load_lds(
        (const __attribute__((address_space(1))) uint*)g,
        (__attribute__((address_space(3))) uint*)lds, 16, 0, 0);
}

// ---------------- transpose 1024x1024: out[n][k] = bf16(in[k][n]), in fp32 ------
__global__ void transpose_k(const float* __restrict__ in, ushort* __restrict__ out) {
    __shared__ ushort tile[32][33];
    int x = blockIdx.x * 32 + threadIdx.x;
    int y0 = blockIdx.y * 32;
    for (int i = threadIdx.y; i < 32; i += 8)
        tile[i][threadIdx.x] = f2b(in[(size_t)(y0 + i) * DMODEL + x]);
    __syncthreads();
    int xo = blockIdx.y * 32 + threadIdx.x;
    int yo0 = blockIdx.x * 32;
    for (int i = threadIdx.y; i < 32; i += 8)
        out[(size_t)(yo0 + i) * DMODEL + xo] = tile[threadIdx.x][i];
}

// ---------------- MFMA GEMM 128x128 (full-batch): R7 body, unchanged ------------
template<int AF32>
__global__ __launch_bounds__(256) void gemm128(const void* __restrict__ A, size_t aoff,
                                               const ushort* __restrict__ Bt,
                                               ushort* __restrict__ C, int act,
                                               float* __restrict__ csum) {
    constexpr int SMEM_BYTES = AF32 ? 49152 : 32768;
    __shared__ __align__(16) char smem[SMEM_BYTES];
    char* smA = smem + 16384;

    int nwg = (int)(gridDim.x * gridDim.y);
    int bid = (int)(blockIdx.y * gridDim.x + blockIdx.x);
    int lid = (bid & 7) * (nwg >> 3) + (bid >> 3);
    int n0 = (lid & 7) * 128;                     // gridDim.x == 8
    int m0 = (lid >> 3) * 128;

    int t = threadIdx.x;
    int lane = t & 63, wave = t >> 6;
    int wm = (wave >> 1) * 64, wn = (wave & 1) * 64;
    int fr = lane & 15;            // frag row (A) / col (B)
    int kq = (lane >> 4) * 8;      // k offset within 32-step

    const float*  Af = (const float*)A + aoff;
    const ushort* Ab = (const ushort*)A + aoff;

    int ldsOff[4], rowOf[4], bcB[4];
    #pragma unroll
    for (int r = 0; r < 4; ++r) {
        int o = t * 16 + r * 4096;
        int row = o >> 7;
        ldsOff[r] = o;
        rowOf[r] = row;
        bcB[r] = (o & 127) ^ ((row & 7) << 4);
    }

    f32x4 acc[4][4];
    #pragma unroll
    for (int i = 0; i < 4; ++i)
        #pragma unroll
        for (int j = 0; j < 4; ++j) acc[i][j] = (f32x4){0.f, 0.f, 0.f, 0.f};

    for (int k0 = 0; k0 < DMODEL; k0 += 64) {
        __syncthreads();
        #pragma unroll
        for (int r = 0; r < 4; ++r)
            gld_lds16(smem + ldsOff[r],
                      Bt + (size_t)(n0 + rowOf[r]) * DMODEL + k0 + (bcB[r] >> 1));
        if (AF32) {
            #pragma unroll
            for (int hh = 0; hh < 2; ++hh)
                #pragma unroll
                for (int r = 0; r < 4; ++r)
                    gld_lds16(smA + hh * 16384 + ldsOff[r],
                              Af + (size_t)(m0 + rowOf[r]) * DMODEL + k0 + hh * 32 + (bcB[r] >> 2));
        } else {
            #pragma unroll
            for (int r = 0; r < 4; ++r)
                gld_lds16(smA + ldsOff[r],
                          Ab + (size_t)(m0 + rowOf[r]) * DMODEL + k0 + (bcB[r] >> 1));
        }
        __syncthreads();

        #pragma unroll
        for (int h = 0; h < 2; ++h) {
            bf16x8 av[4], bv[4];
            #pragma unroll
            for (int i = 0; i < 4; ++i) {
                int row = wm + i * 16 + fr;
                int swz = (row & 7) << 4;
                if (AF32) {
                    const char* Ah = smA + h * 16384;
                    int o1 = ((row << 7) + (kq << 2)) ^ swz;
                    int o2 = ((row << 7) + ((kq + 4) << 2)) ^ swz;
                    float4 q0 = *(const float4*)(Ah + o1);
                    float4 q1 = *(const float4*)(Ah + o2);
                    bf16x8 a;
                    a[0] = (__bf16)q0.x; a[1] = (__bf16)q0.y;
                    a[2] = (__bf16)q0.z; a[3] = (__bf16)q0.w;
                    a[4] = (__bf16)q1.x; a[5] = (__bf16)q1.y;
                    a[6] = (__bf16)q1.z; a[7] = (__bf16)q1.w;
                    av[i] = a;
                } else {
                    int k = h * 32 + kq;
                    int o = ((row << 7) + (k << 1)) ^ swz;
                    av[i] = *(const bf16x8*)(smA + o);
                }
            }
            #pragma unroll
            for (int j = 0; j < 4; ++j) {
                int nrow = wn + j * 16 + fr;
                int k = h * 32 + kq;
                int o = ((nrow << 7) + (k << 1)) ^ ((nrow & 7) << 4);
                bv[j] = *(const bf16x8*)(smem + o);
            }
            #pragma unroll
            for (int i = 0; i < 4; ++i)
                #pragma unroll
                for (int j = 0; j < 4; ++j)
                    acc[i][j] = __builtin_amdgcn_mfma_f32_16x16x32_bf16(av[i], bv[j], acc[i][j], 0, 0, 0);
        }
    }

    int rbase = (lane >> 4) * 4;
    int cix = lane & 15;
    float colacc[4] = {0.f, 0.f, 0.f, 0.f};
    #pragma unroll
    for (int i = 0; i < 4; ++i)
        #pragma unroll
        for (int j = 0; j < 4; ++j) {
            int col = n0 + wn + j * 16 + cix;
            #pragma unroll
            for (int r = 0; r < 4; ++r) {
                int row = m0 + wm + i * 16 + rbase + r;
                float v = acc[i][j][r];
                if (act) v = sigmoidf_(v);
                ushort ub = f2b(v);
                C[(size_t)row * DMODEL + col] = ub;
                if (csum) colacc[j] += b2f(ub);
            }
        }
    if (csum) {
        __syncthreads();
        float* cred = (float*)smem;     // [2][128]
        cred[t] = 0.f;
        __syncthreads();
        #pragma unroll
        for (int j = 0; j < 4; ++j) {
            float s = colacc[j];
            s += __shfl_xor(s, 16);
            s += __shfl_xor(s, 32);
            if (lane < 16) cred[(wm >> 6) * 128 + wn + j * 16 + lane] = s;
        }
        __syncthreads();
        if (t < 128) {
            float tot = cred[t] + cred[128 + t];
            int col = n0 + t;
            int b = m0 >> 12;
            atomicAdd(&csum[((size_t)b * NHEAD + (col >> 6)) * 64 + (col & 63)], tot);
        }
    }
}

// ---------------- MFMA GEMM 64x64 (per-batch / z-batched) -----------------------
// 4 waves 2x2, each wave 32x32 via 2x2 mfma 16x16x32 bf16, BK=64.
// LDS 24KB (AF32) / 16KB (bf16). Same swizzle discipline as gemm128.
// z-batching: A index = aoff + z*BATSTRIDE; C = (z==0 ? C0 : C1+(z-1)*BATSTRIDE).
template<int AF32>
__global__ __launch_bounds__(256) void gemm64(const void* __restrict__ A, size_t aoff,
                                              const ushort* __restrict__ Bt,
                                              ushort* __restrict__ C0,
                                              ushort* __restrict__ C1, int act) {
    constexpr int SMEM_BYTES = AF32 ? 24576 : 16384;
    __shared__ __align__(16) char smem[SMEM_BYTES];
    char* smA = smem + 8192;

    int z = (int)blockIdx.z;
    size_t zoff = aoff + (size_t)z * BATSTRIDE;
    ushort* C = z ? C1 + (size_t)(z - 1) * BATSTRIDE : C0;

    int nwg = (int)(gridDim.x * gridDim.y);                  // 1024
    int bid = (int)(blockIdx.y * gridDim.x + blockIdx.x);
    int lid = (bid & 7) * (nwg >> 3) + (bid >> 3);
    int n0 = (lid & 15) * 64;                                // gridDim.x == 16
    int m0 = (lid >> 4) * 64;

    int t = threadIdx.x;
    int lane = t & 63, wave = t >> 6;
    int wm = (wave >> 1) * 32, wn = (wave & 1) * 32;
    int fr = lane & 15;
    int kq = (lane >> 4) * 8;

    const float*  Af = (const float*)A + zoff;
    const ushort* Ab = (const ushort*)A + zoff;

    f32x4 acc[2][2];
    #pragma unroll
    for (int i = 0; i < 2; ++i)
        #pragma unroll
        for (int j = 0; j < 2; ++j) acc[i][j] = (f32x4){0.f, 0.f, 0.f, 0.f};

    for (int k0 = 0; k0 < DMODEL; k0 += 64) {
        __syncthreads();
        #pragma unroll
        for (int r = 0; r < 2; ++r) {
            int o = t * 16 + r * 4096;
            int row = o >> 7;
            int cb = (o & 127) ^ ((row & 7) << 4);
            gld_lds16(smem + o, Bt + (size_t)(n0 + row) * DMODEL + k0 + (cb >> 1));
        }
        if (AF32) {
            #pragma unroll
            for (int r = 0; r < 4; ++r) {
                int o = t * 16 + r * 4096;
                int row = o >> 8;
                int cb = (o & 255) ^ ((row & 7) << 4);
                gld_lds16(smA + o, Af + (size_t)(m0 + row) * DMODEL + k0 + (cb >> 2));
            }
        } else {
            #pragma unroll
            for (int r = 0; r < 2; ++r) {
                int o = t * 16 + r * 4096;
                int row = o >> 7;
                int cb = (o & 127) ^ ((row & 7) << 4);
                gld_lds16(smA + o, Ab + (size_t)(m0 + row) * DMODEL + k0 + (cb >> 1));
            }
        }
        __syncthreads();   // vmcnt(0) drain

        #pragma unroll
        for (int h = 0; h < 2; ++h) {
            bf16x8 av[2], bv[2];
            #pragma unroll
            for (int i = 0; i < 2; ++i) {
                int row = wm + i * 16 + fr;
                int swz = (row & 7) << 4;
                if (AF32) {
                    int k = h * 32 + kq;
                    int o1 = ((row << 8) + (k << 2)) ^ swz;
                    int o2 = ((row << 8) + ((k + 4) << 2)) ^ swz;
                    float4 q0 = *(const float4*)(smA + o1);
                    float4 q1 = *(const float4*)(smA + o2);
                    bf16x8 a;
                    a[0] = (__bf16)q0.x; a[1] = (__bf16)q0.y;
                    a[2] = (__bf16)q0.z; a[3] = (__bf16)q0.w;
                    a[4] = (__bf16)q1.x; a[5] = (__bf16)q1.y;
                    a[6] = (__bf16)q1.z; a[7] = (__bf16)q1.w;
                    av[i] = a;
                } else {
                    int k = h * 32 + kq;
                    int o = ((row << 7) + (k << 1)) ^ swz;
                    av[i] = *(const bf16x8*)(smA + o);
                }
            }
            #pragma unroll
            for (int j = 0; j < 2; ++j) {
                int nrow = wn + j * 16 + fr;
                int k = h * 32 + kq;
                int o = ((nrow << 7) + (k << 1)) ^ ((nrow & 7) << 4);
                bv[j] = *(const bf16x8*)(smem + o);
            }
            #pragma unroll
            for (int i = 0; i < 2; ++i)
                #pragma unroll
                for (int j = 0; j < 2; ++j)
                    acc[i][j] = __builtin_amdgcn_mfma_f32_16x16x32_bf16(av[i], bv[j], acc[i][j], 0, 0, 0);
        }
    }

    int rbase = (lane >> 4) * 4;
    int cix = lane & 15;
    #pragma unroll
    for (int i = 0; i < 2; ++i)
        #pragma unroll
        for (int j = 0; j < 2; ++j) {
            int col = n0 + wn + j * 16 + cix;
            #pragma unroll
            for (int r = 0; r < 4; ++r) {
                int row = m0 + wm + i * 16 + rbase + r;
                float v = acc[i][j][r];
                if (act) v = sigmoidf_(v);
                C[(size_t)row * DMODEL + col] = f2b(v);
            }
        }
}

// ---- fused dots1 + weighted colsum2, batched over b (z) ----
__global__ void dots1_k(const ushort* __restrict__ Q, const ushort* __restrict__ K,
                        const float* __restrict__ Qsum, const float* __restrict__ Ksum,
                        float* __restrict__ si_out, float* __restrict__ qsi,
                        float* __restrict__ kso) {
    int h = blockIdx.x, b = blockIdx.z;
    int lane = threadIdx.x & 63, wv = threadIdx.x >> 6;
    const ushort* qp = Q + (size_t)b * BROWS * DMODEL + h * 64 + lane;
    const ushort* kp = K + (size_t)b * BROWS * DMODEL + h * 64 + lane;
    float vql = Ksum[((size_t)b * NHEAD + h) * 64 + lane];
    float vkl = Qsum[((size_t)b * NHEAD + h) * 64 + lane];
    float* sip = si_out + ((size_t)b * NHEAD + h) * S_LEN;
    int s0 = blockIdx.y * 128 + wv * 32;
    float aq = 0.f, ak = 0.f;
    for (int i = 0; i < 32; ++i) {
        int s = s0 + i;
        float qv = b2f(qp[(size_t)s * DMODEL]);
        float kv = b2f(kp[(size_t)s * DMODEL]);
        float dq = qv * vql, dk = kv * vkl;
        #pragma unroll
        for (int off = 32; off; off >>= 1) {
            dq += __shfl_xor(dq, off);
            dk += __shfl_xor(dk, off);
        }
        float si_ = 1.f / dq, so_ = 1.f / dk;
        if (lane == 0) sip[s] = si_;
        aq += qv * si_;
        ak += kv * so_;
    }
    atomicAdd(&qsi[((size_t)b * NHEAD + h) * 64 + lane], aq);
    atomicAdd(&kso[((size_t)b * NHEAD + h) * 64 + lane], ak);
}

// ---- per-s dots with a per-head 64-vector, batched over b (z) ----
__global__ void dots_k(const ushort* __restrict__ Q, const ushort* __restrict__ K,
                       const float* __restrict__ vq, const float* __restrict__ vk,
                       float* __restrict__ outq, float* __restrict__ outk, int invert) {
    int h = blockIdx.x;
    int b = blockIdx.z;
    const ushort* Qb = Q + (size_t)b * BROWS * DMODEL;
    const ushort* Kb = K + (size_t)b * BROWS * DMODEL;
    const float* vqb = vq + (size_t)b * NHEAD * 64;
    const float* vkb = vk + (size_t)b * NHEAD * 64;
    float* oq = outq + (size_t)b * NHEAD * S_LEN;
    float* ok = outk + (size_t)b * NHEAD * S_LEN;
    int lane = threadIdx.x & 63, wv = threadIdx.x >> 6;
    const ushort* qp = Qb + h * 64 + lane;
    const ushort* kp = Kb + h * 64 + lane;
    float vql = vqb[h * 64 + lane];
    float vkl = vkb[h * 64 + lane];
    int s0 = blockIdx.y * 128 + wv * 32;
    for (int i = 0; i < 32; ++i) {
        int s = s0 + i;
        float dq = b2f(qp[(size_t)s * DMODEL]) * vql;
        float dk = b2f(kp[(size_t)s * DMODEL]) * vkl;
        #pragma unroll
        for (int off = 32; off; off >>= 1) {
            dq += __shfl_xor(dq, off);
            dk += __shfl_xor(dk, off);
        }
        if (lane == 0) {
            oq[(size_t)h * S_LEN + s] = invert ? 1.f / dq : dq;
            ok[(size_t)h * S_LEN + s] = invert ? 1.f / dk : dk;
        }
    }
}

// ---- softmax over S per head, batched over b (y); safe in-place (w may == x) ----
__global__ void softmax_k(const float* x, float* w) {
    int h = blockIdx.x;
    int b = blockIdx.y;
    const float* xp = x + ((size_t)b * NHEAD + h) * S_LEN;
    float* wp = w + ((size_t)b * NHEAD + h) * S_LEN;
    float loc[16];
    float mx = -1e30f;
    #pragma unroll
    for (int i = 0; i < 16; ++i) { loc[i] = xp[threadIdx.x + i * 256]; mx = fmaxf(mx, loc[i]); }
    __shared__ float red[256];
    red[threadIdx.x] = mx; __syncthreads();
    for (int st = 128; st; st >>= 1) {
        if (threadIdx.x < st) red[threadIdx.x] = fmaxf(red[threadIdx.x], red[threadIdx.x + st]);
        __syncthreads();
    }
    mx = red[0]; __syncthreads();
    float sm = 0.f;
    #pragma unroll
    for (int i = 0; i < 16; ++i) { loc[i] = __expf(loc[i] - mx); sm += loc[i]; }
    red[threadIdx.x] = sm; __syncthreads();
    for (int st = 128; st; st >>= 1) {
        if (threadIdx.x < st) red[threadIdx.x] += red[threadIdx.x + st];
        __syncthreads();
    }
    float inv = 1.f / red[0];
    #pragma unroll
    for (int i = 0; i < 16; ++i)
        wp[threadIdx.x + i * 256] = loc[i] * inv;
}

// ---- kv[h,k,v] = sum_s (K[s,k]*w[h,s]) * V[s,v], one batch (split-S atomics) ----
// Grid (16,32) = 512 blocks. Bijective XCD remap; each block does 128 s.
__global__ __launch_bounds__(256) void kv_k(const ushort* __restrict__ K,
                                            const ushort* __restrict__ V,
                                            const float* __restrict__ w,
                                            float* __restrict__ kv) {
    int bid = (int)(blockIdx.y * gridDim.x + blockIdx.x);   // gridDim = (16, 32)
    int lid = (bid & 7) * 64 + (bid >> 3);                  // [0,512) bijective
    int h = lid & 15;
    int sy = lid >> 4;                                      // [0,32)
    __shared__ __align__(16) float  KwS[64 * 64];
    __shared__ __align__(16) ushort Vt[64 * 64];
    int t = threadIdx.x;
    int kk = (t & 31) * 2;
    int v0 = (t >> 5) * 8;
    float acc[2][8];
    #pragma unroll
    for (int i = 0; i < 2; ++i)
        #pragma unroll
        for (int j = 0; j < 8; ++j) acc[i][j] = 0.f;
    int sl_s = t >> 2, q = t & 3;
    int sBase = sy * (S_LEN / KV_SPLIT);                    // 128 rows per block
    for (int t0 = 0; t0 < S_LEN / KV_SPLIT; t0 += 64) {
        __syncthreads();
        #pragma unroll
        for (int r = 0; r < 2; ++r) {
            int o = t * 16 + r * 4096;
            int row = o >> 7;
            gld_lds16((char*)Vt + o,
                      V + (size_t)(sBase + t0 + row) * DMODEL + h * 64 + ((o & 127) >> 1));
        }
        {
            int s = sBase + t0 + sl_s;
            float ws = w[(size_t)h * S_LEN + s];
            const ushort* kp = K + (size_t)s * DMODEL + h * 64 + q * 16;
            uint4 ka = *(const uint4*)kp;
            uint4 kb = *(const uint4*)(kp + 8);
            int swz = (sl_s & 7) << 4;
            char* base = (char*)KwS + sl_s * 256;
            f32x4 c0 = { blo(ka.x) * ws, bhi(ka.x) * ws, blo(ka.y) * ws, bhi(ka.y) * ws };
            f32x4 c1 = { blo(ka.z) * ws, bhi(ka.z) * ws, blo(ka.w) * ws, bhi(ka.w) * ws };
            f32x4 c2 = { blo(kb.x) * ws, bhi(kb.x) * ws, blo(kb.y) * ws, bhi(kb.y) * ws };
            f32x4 c3 = { blo(kb.z) * ws, bhi(kb.z) * ws, blo(kb.w) * ws, bhi(kb.w) * ws };
            *(f32x4*)(base + ((q * 64 +  0) ^ swz)) = c0;
            *(f32x4*)(base + ((q * 64 + 16) ^ swz)) = c1;
            *(f32x4*)(base + ((q * 64 + 32) ^ swz)) = c2;
            *(f32x4*)(base + ((q * 64 + 48) ^ swz)) = c3;
        }
        __syncthreads();
        #pragma unroll 2
        for (int sl = 0; sl < 64; ++sl) {
            int swz = (sl & 7) << 4;
            float2 kf = *(const float2*)((const char*)KwS + sl * 256 + ((kk * 4) ^ swz));
            uint4 vv = *(const uint4*)((const char*)Vt + sl * 128 + v0 * 2);
            float vf0 = blo(vv.x), vf1 = bhi(vv.x), vf2 = blo(vv.y), vf3 = bhi(vv.y);
            float vf4 = blo(vv.z), vf5 = bhi(vv.z), vf6 = blo(vv.w), vf7 = bhi(vv.w);
            acc[0][0] += kf.x * vf0; acc[0][1] += kf.x * vf1;
            acc[0][2] += kf.x * vf2; acc[0][3] += kf.x * vf3;
            acc[0][4] += kf.x * vf4; acc[0][5] += kf.x * vf5;
            acc[0][6] += kf.x * vf6; acc[0][7] += kf.x * vf7;
            acc[1][0] += kf.y * vf0; acc[1][1] += kf.y * vf1;
            acc[1][2] += kf.y * vf2; acc[1][3] += kf.y * vf3;
            acc[1][4] += kf.y * vf4; acc[1][5] += kf.y * vf5;
            acc[1][6] += kf.y * vf6; acc[1][7] += kf.y * vf7;
        }
    }
    float* kvp = kv + (size_t)h * 4096;
    #pragma unroll
    for (int i = 0; i < 2; ++i)
        #pragma unroll
        for (int j = 0; j < 8; ++j)
            atomicAdd(&kvp[(kk + i) * 64 + v0 + j], acc[i][j]);
}

// ---- ctx[s,h*64+v] = sig(csink)*si*sum_k Q[s,k]*kv[k,v]; batched over b (z) ----
// Grid (16,32,4); per z: 512 blocks, each 128 s (2 tiles of 64).
__global__ __launch_bounds__(256) void ctx_k(const ushort* __restrict__ Qall,
                                             const float* __restrict__ kv4,
                                             const float* __restrict__ siAll,
                                             const float* __restrict__ cskAll,
                                             ushort* __restrict__ ctxAll) {
    int b = (int)blockIdx.z;
    const ushort* Q = Qall + (size_t)b * BATSTRIDE;
    const float* kv = kv4 + (size_t)b * NHEAD * 4096;
    const float* si = siAll + (size_t)b * NHEAD * S_LEN;
    const float* csink = cskAll + (size_t)b * NHEAD * S_LEN;
    ushort* ctx = ctxAll + (size_t)b * BATSTRIDE;

    int bid = (int)(blockIdx.y * gridDim.x + blockIdx.x);   // gridDim = (16, 32)
    int lid = (bid & 7) * 64 + (bid >> 3);                  // [0,512) bijective
    int h = lid & 15;
    int sBlock = (lid >> 4) * 128;
    __shared__ __align__(16) float  kvf[64 * 64];   // [k][v] linear
    __shared__ __align__(16) ushort Qt[64 * 64];    // [s][k] source-preswizzled
    int t = threadIdx.x;
    {
        const float* kp = kv + (size_t)h * 4096;
        #pragma unroll
        for (int i = 0; i < 4; ++i) {
            int idx = t * 4 + i * 1024;
            *(f32x4*)&kvf[idx] = *(const f32x4*)&kp[idx];
        }
    }
    int spair = t >> 3;
    int v0 = (t & 7) * 8;
    for (int tile = 0; tile < 2; ++tile) {
        __syncthreads();
        int sT = sBlock + tile * 64;
        #pragma unroll
        for (int r = 0; r < 2; ++r) {
            int o = t * 16 + r * 4096;
            int row = o >> 7;
            int cb = (o & 127) ^ ((row & 7) << 4);
            gld_lds16((char*)Qt + o, Q + (size_t)(sT + row) * DMODEL + h * 64 + (cb >> 1));
        }
        __syncthreads();
        int s0 = spair * 2, s1 = s0 + 1;
        int swz0 = (s0 & 7) << 4, swz1 = (s1 & 7) << 4;
        float acc0[8], acc1[8];
        #pragma unroll
        for (int j = 0; j < 8; ++j) { acc0[j] = 0.f; acc1[j] = 0.f; }
        #pragma unroll 4
        for (int k = 0; k < 64; k += 4) {
            union { ushort4 v; ushort u[4]; } qa, qb;
            qa.v = *(const ushort4*)((const char*)Qt + s0 * 128 + ((k * 2) ^ swz0));
            qb.v = *(const ushort4*)((const char*)Qt + s1 * 128 + ((k * 2) ^ swz1));
            const char* rbase = (const char*)kvf + k * 256 + v0 * 4;
            #pragma unroll
            for (int kk2 = 0; kk2 < 4; ++kk2) {
                f32x4 r0 = *(const f32x4*)(rbase + kk2 * 256);
                f32x4 r1 = *(const f32x4*)(rbase + kk2 * 256 + 16);
                float qaf = b2f(qa.u[kk2]);
                float qbf = b2f(qb.u[kk2]);
                #pragma unroll
                for (int j = 0; j < 4; ++j) {
                    acc0[j]     += qaf * r0[j];
                    acc0[4 + j] += qaf * r1[j];
                    acc1[j]     += qbf * r0[j];
                    acc1[4 + j] += qbf * r1[j];
                }
            }
        }
        int gs0 = sT + s0, gs1 = sT + s1;
        float sc0 = si[(size_t)h * S_LEN + gs0] * sigmoidf_(csink[(size_t)h * S_LEN + gs0]);
        float sc1 = si[(size_t)h * S_LEN + gs1] * sigmoidf_(csink[(size_t)h * S_LEN + gs1]);
        union { ushort u[8]; uint4 v; } o0, o1;
        #pragma unroll
        for (int j = 0; j < 8; ++j) {
            o0.u[j] = f2b(acc0[j] * sc0);
            o1.u[j] = f2b(acc1[j] * sc1);
        }
        *(uint4*)(ctx + (size_t)gs0 * DMODEL + h * 64 + v0) = o0.v;
        *(uint4*)(ctx + (size_t)gs1 * DMODEL + h * 64 + v0) = o1.v;
    }
}

// ---- LayerNorm(y_bf16 + residual_f32) * gamma + beta -> fp32 out (per-row) ----
__global__ void ln_k(const ushort* __restrict__ y, const float* __restrict__ res,
                     const float* __restrict__ gamma, const float* __restrict__ beta,
                     float* __restrict__ out) {
    size_t row = blockIdx.x;
    const ushort* yp = y + row * DMODEL;
    const float* rp = res + row * DMODEL;
    float x[4];
    float s = 0.f, s2 = 0.f;
    #pragma unroll
    for (int i = 0; i < 4; ++i) {
        int d = threadIdx.x + i * 256;
        x[i] = b2f(yp[d]) + rp[d];
        s += x[i]; s2 += x[i] * x[i];
    }
    __shared__ float r1[256], r2[256];
    r1[threadIdx.x] = s; r2[threadIdx.x] = s2;
    __syncthreads();
    for (int st = 128; st; st >>= 1) {
        if (threadIdx.x < st) { r1[threadIdx.x] += r1[threadIdx.x + st]; r2[threadIdx.x] += r2[threadIdx.x + st]; }
        __syncthreads();
    }
    float mean = r1[0] * (1.f / DMODEL);
    float var = r2[0] * (1.f / DMODEL) - mean * mean;
    float rstd = rsqrtf(var + 1e-5f);
    #pragma unroll
    for (int i = 0; i < 4; ++i) {
        int d = threadIdx.x + i * 256;
        out[row * DMODEL + d] = (x[i] - mean) * rstd * gamma[d] + beta[d];
    }
}

extern "C" void kernel_launch(void* const* d_in, const int* in_sizes, int n_in,
                              void* d_out, int out_size, void* d_ws, size_t ws_size,
                              hipStream_t stream) {
    const float* inQ  = (const float*)d_in[0];
    const float* inK  = (const float*)d_in[1];
    const float* inV  = (const float*)d_in[2];
    const float* WQ   = (const float*)d_in[3];
    const float* WK   = (const float*)d_in[4];
    const float* WV   = (const float*)d_in[5];
    const float* WF   = (const float*)d_in[6];
    const float* gamma= (const float*)d_in[7];
    const float* beta = (const float*)d_in[8];
    float* outf = (float*)d_out;

    // d_out scratch: bf16 Q at [0,32MB), bf16 K/ctx at [32,64MB)
    ushort* Qb  = (ushort*)d_out;
    ushort* KCb = (ushort*)d_out + (size_t)NROWS * DMODEL;

    // d_ws layout (peak 14.06MB; prior proven 13.6MB — +3%):
    const size_t MB = 1024ull * 1024ull;
    char* w = (char*)d_ws;
    ushort* Vb  = (ushort*)w;                 // [4096][1024] bf16, 8MB; later O_0 slot
    ushort* Wt  = (ushort*)(w + 8 * MB);      // 2MB weight^T slot (WQ->WK->WV->WF)
    float* si    = (float*)(w + 10 * MB);     // [4][16][4096] f32, 1MB
    float* soCsk = si + 4 * NHEAD * S_LEN;    // 1MB: csk (dots2)
    float* css   = soCsk + 4 * NHEAD * S_LEN; // 1MB: css -> smw (softmax in-place)
    float* Qsum  = css + 4 * NHEAD * S_LEN;   // 4 sum buffers x [4][16][64] = 64KB
    float* Ksum  = Qsum + 4 * NHEAD * 64;
    float* QsI   = Ksum + 4 * NHEAD * 64;
    float* KsO   = QsI  + 4 * NHEAD * 64;
    float* kvb4  = KsO  + 4 * NHEAD * 64;     // [4][16][64][64] f32, 1MB (per-batch)
    size_t sumZeroBytes = 4 * 4 * NHEAD * 64 * sizeof(float);       // 64KB
    size_t kvZeroBytes  = 4ull * NHEAD * 4096 * sizeof(float);      // 1MB

    dim3 tb(32, 8);
    dim3 tg(32, 32);
    dim3 ggFull(DMODEL / 128, NROWS / 128);   // (8, 128)
    dim3 ggB64(DMODEL / 64, BROWS / 64, 1);   // (16, 64) per batch
    dim3 ggB64z4(DMODEL / 64, BROWS / 64, 4); // batched P3

    // zero Qsum/Ksum/QsI/KsO before gemm epilogue atomics; all kvb once
    hipMemsetAsync(Qsum, 0, sumZeroBytes, stream);
    hipMemsetAsync(kvb4, 0, kvZeroBytes, stream);

    // Phase 1: Q and K projections (full batch) into d_out; epilogue colsums
    transpose_k<<<tg, tb, 0, stream>>>(WQ, Wt);
    gemm128<1><<<ggFull, 256, 0, stream>>>(inQ, 0, Wt, Qb, 1, Qsum);
    transpose_k<<<tg, tb, 0, stream>>>(WK, Wt);
    gemm128<1><<<ggFull, 256, 0, stream>>>(inK, 0, Wt, KCb, 1, Ksum);
    transpose_k<<<tg, tb, 0, stream>>>(WV, Wt);   // WVt stays through P2

    // Stats: fused dots1(+colsum2), dots2, softmax — all 4 batches per launch
    dots1_k<<<dim3(NHEAD, 32, 4), 256, 0, stream>>>(Qb, KCb, Qsum, Ksum, si, QsI, KsO);
    dots_k<<<dim3(NHEAD, 32, 4), 256, 0, stream>>>(Qb, KCb, KsO, QsI, soCsk, css, 0);
    softmax_k<<<dim3(NHEAD, 4), 256, 0, stream>>>(css, css);

    // Phase 2a: per-batch V projection + kv (Vb shared -> serialized pairs)
    for (int b = 0; b < 4; ++b) {
        size_t rowOff = (size_t)b * BATSTRIDE;
        size_t statOff = (size_t)b * NHEAD * S_LEN;
        gemm64<1><<<ggB64, 256, 0, stream>>>(inV, rowOff, Wt, Vb, Vb, 0);
        kv_k<<<dim3(NHEAD, KV_SPLIT), 256, 0, stream>>>(KCb + rowOff, Vb,
                                                        css + statOff,
                                                        kvb4 + (size_t)b * NHEAD * 4096);
    }
    // Phase 2b: batched ctx (all b): reads Qb/kvb4/si/csk, overwrites dead K_b
    ctx_k<<<dim3(NHEAD, KV_SPLIT, 4), 256, 0, stream>>>(Qb, kvb4, si, soCsk, KCb);

    // Phase 3: ONE batched output-projection gemm (z=4), then ln in order 3,2,1,0.
    // O placement: z=0->Vb (dead), z>=1 -> Qb+(z-1)*8MB (Q dead after ctx).
    transpose_k<<<tg, tb, 0, stream>>>(WF, Wt);   // WVt dead now
    gemm64<0><<<ggB64z4, 256, 0, stream>>>(KCb, 0, Wt, Vb, Qb, 0);
    // ln order (clobber-safe, audited):
    //   ln3: reads O3=Qb+16MB, writes out[48,64) (ctx2/3 consumed by gemm)
    //   ln2: reads O2=Qb+8MB,  writes out[32,48) (ctx0/1 consumed)
    //   ln1: reads O1=Qb+0,    writes out[16,32) (O3 consumed by ln3)
    //   ln0: reads O0=Vb,      writes out[0,16)  (O1,O2 consumed by ln1,ln2)
    ln_k<<<BROWS, 256, 0, stream>>>(Qb + 2 * BATSTRIDE, inQ + 3 * BATSTRIDE,
                                    gamma, beta, outf + 3 * BATSTRIDE);
    ln_k<<<BROWS, 256, 0, stream>>>(Qb + 1 * BATSTRIDE, inQ + 2 * BATSTRIDE,
                                    gamma, beta, outf + 2 * BATSTRIDE);
    ln_k<<<BROWS, 256, 0, stream>>>(Qb, inQ + 1 * BATSTRIDE,
                                    gamma, beta, outf + 1 * BATSTRIDE);
    ln_k<<<BROWS, 256, 0, stream>>>(Vb, inQ, gamma, beta, outf);
}

// Round 10
// 870.888 us; speedup vs baseline: 1.0845x; 1.0452x over previous
//
#include <hip/hip_runtime.h>
#include <hip/hip_bf16.h>

// FlowAttention: B=4 S=4096 D=1024 H=16 dk=dv=64. Inputs/outputs fp32.
// Round-15: stats vectorization + P3 via z-batched gemm128.
//  - dots1_k/dots_k rewritten (G13): 8 lanes per s, uint4(=8 bf16) loads,
//    3-shfl butterfly dot, per-dim accs reduced by shfl_xor(8,16,32) then
//    8-lane atomics. 8x bytes/instruction vs the 2B/lane serial version.
//  - P3: one gemm128z launch (bf16 gemm128 body, z=4; C: z=0->Vb,
//    z>=1->Qb+(z-1)*8MB — R8's proven placement) replacing gemm64 z4.
//    ln order 3,2,1,0 unchanged (clobber-safe, audited in R8/R9).
//  - gemm128 (full-batch), gemm64 (V-proj), kv_k, ctx_k, softmax, ln: unchanged.
#define S_LEN 4096
#define DMODEL 1024
#define NHEAD 16
#define NROWS 16384      // B*S
#define BROWS 4096       // rows per batch
#define KV_SPLIT 32
#define BATSTRIDE 4194304ull   // elements per batch slice (4096*1024)

typedef __bf16 bf16x8 __attribute__((ext_vector_type(8)));
typedef float  f32x4  __attribute__((ext_vector_type(4)));

__device__ __forceinline__ float b2f(ushort u) {
    union { uint i; float f; } c; c.i = ((uint)u) << 16; return c.f;
}
__device__ __forceinline__ float blo(uint u) {
    union { uint i; float f; } c; c.i = u << 16; return c.f;
}
__device__ __forceinline__ float bhi(uint u) {
    union { uint i; float f; } c; c.i = u & 0xFFFF0000u; return c.f;
}
__device__ __forceinline__ ushort f2b(float f) {
    union { uint i; float f; } c; c.f = f;
    uint r = c.i + 0x7FFF + ((c.i >> 16) & 1);   // round-to-nearest-even
    return (ushort)(r >> 16);
}
__device__ __forceinline__ float sigmoidf_(float x) {
    return 1.f / (1.f + __expf(-x));
}

// async 16B global->LDS DMA. Dest must be thread-linear (base + tid*16).
__device__ __forceinline__ void gld_lds16(void* lds, const void* g) {
    __builtin_amdgcn_global_load_lds(
        (const __attribute__((address_space(1))) uint*)g,
        (__attribute__((address_space(3))) uint*)lds, 16, 0, 0);
}

// ---------------- transpose 1024x1024: out[n][k] = bf16(in[k][n]), in fp32 ------
__global__ void transpose_k(const float* __restrict__ in, ushort* __restrict__ out) {
    __shared__ ushort tile[32][33];
    int x = blockIdx.x * 32 + threadIdx.x;
    int y0 = blockIdx.y * 32;
    for (int i = threadIdx.y; i < 32; i += 8)
        tile[i][threadIdx.x] = f2b(in[(size_t)(y0 + i) * DMODEL + x]);
    __syncthreads();
    int xo = blockIdx.y * 32 + threadIdx.x;
    int yo0 = blockIdx.x * 32;
    for (int i = threadIdx.y; i < 32; i += 8)
        out[(size_t)(yo0 + i) * DMODEL + xo] = tile[threadIdx.x][i];
}

// ---------------- MFMA GEMM 128x128 (full-batch): R7 body, unchanged ------------
template<int AF32>
__global__ __launch_bounds__(256) void gemm128(const void* __restrict__ A, size_t aoff,
                                               const ushort* __restrict__ Bt,
                                               ushort* __restrict__ C, int act,
                                               float* __restrict__ csum) {
    constexpr int SMEM_BYTES = AF32 ? 49152 : 32768;
    __shared__ __align__(16) char smem[SMEM_BYTES];
    char* smA = smem + 16384;

    int nwg = (int)(gridDim.x * gridDim.y);
    int bid = (int)(blockIdx.y * gridDim.x + blockIdx.x);
    int lid = (bid & 7) * (nwg >> 3) + (bid >> 3);
    int n0 = (lid & 7) * 128;                     // gridDim.x == 8
    int m0 = (lid >> 3) * 128;

    int t = threadIdx.x;
    int lane = t & 63, wave = t >> 6;
    int wm = (wave >> 1) * 64, wn = (wave & 1) * 64;
    int fr = lane & 15;            // frag row (A) / col (B)
    int kq = (lane >> 4) * 8;      // k offset within 32-step

    const float*  Af = (const float*)A + aoff;
    const ushort* Ab = (const ushort*)A + aoff;

    int ldsOff[4], rowOf[4], bcB[4];
    #pragma unroll
    for (int r = 0; r < 4; ++r) {
        int o = t * 16 + r * 4096;
        int row = o >> 7;
        ldsOff[r] = o;
        rowOf[r] = row;
        bcB[r] = (o & 127) ^ ((row & 7) << 4);
    }

    f32x4 acc[4][4];
    #pragma unroll
    for (int i = 0; i < 4; ++i)
        #pragma unroll
        for (int j = 0; j < 4; ++j) acc[i][j] = (f32x4){0.f, 0.f, 0.f, 0.f};

    for (int k0 = 0; k0 < DMODEL; k0 += 64) {
        __syncthreads();
        #pragma unroll
        for (int r = 0; r < 4; ++r)
            gld_lds16(smem + ldsOff[r],
                      Bt + (size_t)(n0 + rowOf[r]) * DMODEL + k0 + (bcB[r] >> 1));
        if (AF32) {
            #pragma unroll
            for (int hh = 0; hh < 2; ++hh)
                #pragma unroll
                for (int r = 0; r < 4; ++r)
                    gld_lds16(smA + hh * 16384 + ldsOff[r],
                              Af + (size_t)(m0 + rowOf[r]) * DMODEL + k0 + hh * 32 + (bcB[r] >> 2));
        } else {
            #pragma unroll
            for (int r = 0; r < 4; ++r)
                gld_lds16(smA + ldsOff[r],
                          Ab + (size_t)(m0 + rowOf[r]) * DMODEL + k0 + (bcB[r] >> 1));
        }
        __syncthreads();

        #pragma unroll
        for (int h = 0; h < 2; ++h) {
            bf16x8 av[4], bv[4];
            #pragma unroll
            for (int i = 0; i < 4; ++i) {
                int row = wm + i * 16 + fr;
                int swz = (row & 7) << 4;
                if (AF32) {
                    const char* Ah = smA + h * 16384;
                    int o1 = ((row << 7) + (kq << 2)) ^ swz;
                    int o2 = ((row << 7) + ((kq + 4) << 2)) ^ swz;
                    float4 q0 = *(const float4*)(Ah + o1);
                    float4 q1 = *(const float4*)(Ah + o2);
                    bf16x8 a;
                    a[0] = (__bf16)q0.x; a[1] = (__bf16)q0.y;
                    a[2] = (__bf16)q0.z; a[3] = (__bf16)q0.w;
                    a[4] = (__bf16)q1.x; a[5] = (__bf16)q1.y;
                    a[6] = (__bf16)q1.z; a[7] = (__bf16)q1.w;
                    av[i] = a;
                } else {
                    int k = h * 32 + kq;
                    int o = ((row << 7) + (k << 1)) ^ swz;
                    av[i] = *(const bf16x8*)(smA + o);
                }
            }
            #pragma unroll
            for (int j = 0; j < 4; ++j) {
                int nrow = wn + j * 16 + fr;
                int k = h * 32 + kq;
                int o = ((nrow << 7) + (k << 1)) ^ ((nrow & 7) << 4);
                bv[j] = *(const bf16x8*)(smem + o);
            }
            #pragma unroll
            for (int i = 0; i < 4; ++i)
                #pragma unroll
                for (int j = 0; j < 4; ++j)
                    acc[i][j] = __builtin_amdgcn_mfma_f32_16x16x32_bf16(av[i], bv[j], acc[i][j], 0, 0, 0);
        }
    }

    int rbase = (lane >> 4) * 4;
    int cix = lane & 15;
    float colacc[4] = {0.f, 0.f, 0.f, 0.f};
    #pragma unroll
    for (int i = 0; i < 4; ++i)
        #pragma unroll
        for (int j = 0; j < 4; ++j) {
            int col = n0 + wn + j * 16 + cix;
            #pragma unroll
            for (int r = 0; r < 4; ++r) {
                int row = m0 + wm + i * 16 + rbase + r;
                float v = acc[i][j][r];
                if (act) v = sigmoidf_(v);
                ushort ub = f2b(v);
                C[(size_t)row * DMODEL + col] = ub;
                if (csum) colacc[j] += b2f(ub);
            }
        }
    if (csum) {
        __syncthreads();
        float* cred = (float*)smem;     // [2][128]
        cred[t] = 0.f;
        __syncthreads();
        #pragma unroll
        for (int j = 0; j < 4; ++j) {
            float s = colacc[j];
            s += __shfl_xor(s, 16);
            s += __shfl_xor(s, 32);
            if (lane < 16) cred[(wm >> 6) * 128 + wn + j * 16 + lane] = s;
        }
        __syncthreads();
        if (t < 128) {
            float tot = cred[t] + cred[128 + t];
            int col = n0 + t;
            int b = m0 >> 12;
            atomicAdd(&csum[((size_t)b * NHEAD + (col >> 6)) * 64 + (col & 63)], tot);
        }
    }
}

// ---------------- MFMA GEMM 128x128, bf16 A, z-batched (P3) ---------------------
// Same body/discipline as gemm128<0>; per z-slice grid (8,32)=256 blocks with
// bijective XCD swizzle; C: z=0 -> C0 (Vb), z>=1 -> C1+(z-1)*BATSTRIDE.
__global__ __launch_bounds__(256) void gemm128z(const ushort* __restrict__ A,
                                                const ushort* __restrict__ Bt,
                                                ushort* __restrict__ C0,
                                                ushort* __restrict__ C1) {
    __shared__ __align__(16) char smem[32768];
    char* smA = smem + 16384;

    int z = (int)blockIdx.z;
    const ushort* Ab = A + (size_t)z * BATSTRIDE;
    ushort* C = z ? C1 + (size_t)(z - 1) * BATSTRIDE : C0;

    int nwg = (int)(gridDim.x * gridDim.y);       // 256 per slice
    int bid = (int)(blockIdx.y * gridDim.x + blockIdx.x);
    int lid = (bid & 7) * (nwg >> 3) + (bid >> 3);
    int n0 = (lid & 7) * 128;
    int m0 = (lid >> 3) * 128;                    // [0, 4096)

    int t = threadIdx.x;
    int lane = t & 63, wave = t >> 6;
    int wm = (wave >> 1) * 64, wn = (wave & 1) * 64;
    int fr = lane & 15;
    int kq = (lane >> 4) * 8;

    int ldsOff[4], rowOf[4], bcB[4];
    #pragma unroll
    for (int r = 0; r < 4; ++r) {
        int o = t * 16 + r * 4096;
        int row = o >> 7;
        ldsOff[r] = o;
        rowOf[r] = row;
        bcB[r] = (o & 127) ^ ((row & 7) << 4);
    }

    f32x4 acc[4][4];
    #pragma unroll
    for (int i = 0; i < 4; ++i)
        #pragma unroll
        for (int j = 0; j < 4; ++j) acc[i][j] = (f32x4){0.f, 0.f, 0.f, 0.f};

    for (int k0 = 0; k0 < DMODEL; k0 += 64) {
        __syncthreads();
        #pragma unroll
        for (int r = 0; r < 4; ++r)
            gld_lds16(smem + ldsOff[r],
                      Bt + (size_t)(n0 + rowOf[r]) * DMODEL + k0 + (bcB[r] >> 1));
        #pragma unroll
        for (int r = 0; r < 4; ++r)
            gld_lds16(smA + ldsOff[r],
                      Ab + (size_t)(m0 + rowOf[r]) * DMODEL + k0 + (bcB[r] >> 1));
        __syncthreads();

        #pragma unroll
        for (int h = 0; h < 2; ++h) {
            bf16x8 av[4], bv[4];
            #pragma unroll
            for (int i = 0; i < 4; ++i) {
                int row = wm + i * 16 + fr;
                int k = h * 32 + kq;
                int o = ((row << 7) + (k << 1)) ^ ((row & 7) << 4);
                av[i] = *(const bf16x8*)(smA + o);
            }
            #pragma unroll
            for (int j = 0; j < 4; ++j) {
                int nrow = wn + j * 16 + fr;
                int k = h * 32 + kq;
                int o = ((nrow << 7) + (k << 1)) ^ ((nrow & 7) << 4);
                bv[j] = *(const bf16x8*)(smem + o);
            }
            #pragma unroll
            for (int i = 0; i < 4; ++i)
                #pragma unroll
                for (int j = 0; j < 4; ++j)
                    acc[i][j] = __builtin_amdgcn_mfma_f32_16x16x32_bf16(av[i], bv[j], acc[i][j], 0, 0, 0);
        }
    }

    int rbase = (lane >> 4) * 4;
    int cix = lane & 15;
    #pragma unroll
    for (int i = 0; i < 4; ++i)
        #pragma unroll
        for (int j = 0; j < 4; ++j) {
            int col = n0 + wn + j * 16 + cix;
            #pragma unroll
            for (int r = 0; r < 4; ++r) {
                int row = m0 + wm + i * 16 + rbase + r;
                C[(size_t)row * DMODEL + col] = f2b(acc[i][j][r]);
            }
        }
}

// ---------------- MFMA GEMM 64x64 (per-batch V-proj) ----------------------------
template<int AF32>
__global__ __launch_bounds__(256) void gemm64(const void* __restrict__ A, size_t aoff,
                                              const ushort* __restrict__ Bt,
                                              ushort* __restrict__ C0,
                                              ushort* __restrict__ C1, int act) {
    constexpr int SMEM_BYTES = AF32 ? 24576 : 16384;
    __shared__ __align__(16) char smem[SMEM_BYTES];
    char* smA = smem + 8192;

    int z = (int)blockIdx.z;
    size_t zoff = aoff + (size_t)z * BATSTRIDE;
    ushort* C = z ? C1 + (size_t)(z - 1) * BATSTRIDE : C0;

    int nwg = (int)(gridDim.x * gridDim.y);                  // 1024
    int bid = (int)(blockIdx.y * gridDim.x + blockIdx.x);
    int lid = (bid & 7) * (nwg >> 3) + (bid >> 3);
    int n0 = (lid & 15) * 64;                                // gridDim.x == 16
    int m0 = (lid >> 4) * 64;

    int t = threadIdx.x;
    int lane = t & 63, wave = t >> 6;
    int wm = (wave >> 1) * 32, wn = (wave & 1) * 32;
    int fr = lane & 15;
    int kq = (lane >> 4) * 8;

    const float*  Af = (const float*)A + zoff;
    const ushort* Ab = (const ushort*)A + zoff;

    f32x4 acc[2][2];
    #pragma unroll
    for (int i = 0; i < 2; ++i)
        #pragma unroll
        for (int j = 0; j < 2; ++j) acc[i][j] = (f32x4){0.f, 0.f, 0.f, 0.f};

    for (int k0 = 0; k0 < DMODEL; k0 += 64) {
        __syncthreads();
        #pragma unroll
        for (int r = 0; r < 2; ++r) {
            int o = t * 16 + r * 4096;
            int row = o >> 7;
            int cb = (o & 127) ^ ((row & 7) << 4);
            gld_lds16(smem + o, Bt + (size_t)(n0 + row) * DMODEL + k0 + (cb >> 1));
        }
        if (AF32) {
            #pragma unroll
            for (int r = 0; r < 4; ++r) {
                int o = t * 16 + r * 4096;
                int row = o >> 8;
                int cb = (o & 255) ^ ((row & 7) << 4);
                gld_lds16(smA + o, Af + (size_t)(m0 + row) * DMODEL + k0 + (cb >> 2));
            }
        } else {
            #pragma unroll
            for (int r = 0; r < 2; ++r) {
                int o = t * 16 + r * 4096;
                int row = o >> 7;
                int cb = (o & 127) ^ ((row & 7) << 4);
                gld_lds16(smA + o, Ab + (size_t)(m0 + row) * DMODEL + k0 + (cb >> 1));
            }
        }
        __syncthreads();   // vmcnt(0) drain

        #pragma unroll
        for (int h = 0; h < 2; ++h) {
            bf16x8 av[2], bv[2];
            #pragma unroll
            for (int i = 0; i < 2; ++i) {
                int row = wm + i * 16 + fr;
                int swz = (row & 7) << 4;
                if (AF32) {
                    int k = h * 32 + kq;
                    int o1 = ((row << 8) + (k << 2)) ^ swz;
                    int o2 = ((row << 8) + ((k + 4) << 2)) ^ swz;
                    float4 q0 = *(const float4*)(smA + o1);
                    float4 q1 = *(const float4*)(smA + o2);
                    bf16x8 a;
                    a[0] = (__bf16)q0.x; a[1] = (__bf16)q0.y;
                    a[2] = (__bf16)q0.z; a[3] = (__bf16)q0.w;
                    a[4] = (__bf16)q1.x; a[5] = (__bf16)q1.y;
                    a[6] = (__bf16)q1.z; a[7] = (__bf16)q1.w;
                    av[i] = a;
                } else {
                    int k = h * 32 + kq;
                    int o = ((row << 7) + (k << 1)) ^ swz;
                    av[i] = *(const bf16x8*)(smA + o);
                }
            }
            #pragma unroll
            for (int j = 0; j < 2; ++j) {
                int nrow = wn + j * 16 + fr;
                int k = h * 32 + kq;
                int o = ((nrow << 7) + (k << 1)) ^ ((nrow & 7) << 4);
                bv[j] = *(const bf16x8*)(smem + o);
            }
            #pragma unroll
            for (int i = 0; i < 2; ++i)
                #pragma unroll
                for (int j = 0; j < 2; ++j)
                    acc[i][j] = __builtin_amdgcn_mfma_f32_16x16x32_bf16(av[i], bv[j], acc[i][j], 0, 0, 0);
        }
    }

    int rbase = (lane >> 4) * 4;
    int cix = lane & 15;
    #pragma unroll
    for (int i = 0; i < 2; ++i)
        #pragma unroll
        for (int j = 0; j < 2; ++j) {
            int col = n0 + wn + j * 16 + cix;
            #pragma unroll
            for (int r = 0; r < 4; ++r) {
                int row = m0 + wm + i * 16 + rbase + r;
                float v = acc[i][j][r];
                if (act) v = sigmoidf_(v);
                C[(size_t)row * DMODEL + col] = f2b(v);
            }
        }
}

// ---- fused dots1 + weighted colsum2, vectorized (8 lanes per s) ----
// Lane: g=lane>>3 (s-subindex), e=lane&7 (dim octet). Per s: uint4 load (8 bf16),
// 8-FMA dot, shfl_xor(1,2,4) butterfly. Per-dim accs reduced shfl_xor(8,16,32),
// atomics from g==0 lanes. Grid (NHEAD, 16, 4), 256 threads.
__global__ void dots1_k(const ushort* __restrict__ Q, const ushort* __restrict__ K,
                        const float* __restrict__ Qsum, const float* __restrict__ Ksum,
                        float* __restrict__ si_out, float* __restrict__ qsi,
                        float* __restrict__ kso) {
    int h = blockIdx.x, b = blockIdx.z;
    int t = threadIdx.x;
    int lane = t & 63, wv = t >> 6;
    int g = lane >> 3, e = lane & 7;
    size_t bh = (size_t)b * NHEAD + h;
    const ushort* qp = Q + (size_t)b * BATSTRIDE + h * 64 + e * 8;
    const ushort* kp = K + (size_t)b * BATSTRIDE + h * 64 + e * 8;
    float4 vq0 = *(const float4*)&Ksum[bh * 64 + e * 8];
    float4 vq1 = *(const float4*)&Ksum[bh * 64 + e * 8 + 4];
    float4 vk0 = *(const float4*)&Qsum[bh * 64 + e * 8];
    float4 vk1 = *(const float4*)&Qsum[bh * 64 + e * 8 + 4];
    float* sip = si_out + bh * S_LEN;
    int sBase = blockIdx.y * 256 + wv * 64 + g;
    float aq[8], ak[8];
    #pragma unroll
    for (int j = 0; j < 8; ++j) { aq[j] = 0.f; ak[j] = 0.f; }
    #pragma unroll 2
    for (int i = 0; i < 8; ++i) {
        int s = sBase + i * 8;
        uint4 qr = *(const uint4*)(qp + (size_t)s * DMODEL);
        uint4 kr = *(const uint4*)(kp + (size_t)s * DMODEL);
        float qf[8] = { blo(qr.x), bhi(qr.x), blo(qr.y), bhi(qr.y),
                        blo(qr.z), bhi(qr.z), blo(qr.w), bhi(qr.w) };
        float kf[8] = { blo(kr.x), bhi(kr.x), blo(kr.y), bhi(kr.y),
                        blo(kr.z), bhi(kr.z), blo(kr.w), bhi(kr.w) };
        float dq = qf[0] * vq0.x + qf[1] * vq0.y + qf[2] * vq0.z + qf[3] * vq0.w
                 + qf[4] * vq1.x + qf[5] * vq1.y + qf[6] * vq1.z + qf[7] * vq1.w;
        float dk = kf[0] * vk0.x + kf[1] * vk0.y + kf[2] * vk0.z + kf[3] * vk0.w
                 + kf[4] * vk1.x + kf[5] * vk1.y + kf[6] * vk1.z + kf[7] * vk1.w;
        dq += __shfl_xor(dq, 1); dq += __shfl_xor(dq, 2); dq += __shfl_xor(dq, 4);
        dk += __shfl_xor(dk, 1); dk += __shfl_xor(dk, 2); dk += __shfl_xor(dk, 4);
        float si_ = 1.f / dq, so_ = 1.f / dk;
        if (e == 0) sip[s] = si_;
        #pragma unroll
        for (int j = 0; j < 8; ++j) {
            aq[j] += qf[j] * si_;
            ak[j] += kf[j] * so_;
        }
    }
    #pragma unroll
    for (int j = 0; j < 8; ++j) {
        float v = aq[j];
        v += __shfl_xor(v, 8); v += __shfl_xor(v, 16); v += __shfl_xor(v, 32);
        float u = ak[j];
        u += __shfl_xor(u, 8); u += __shfl_xor(u, 16); u += __shfl_xor(u, 32);
        if (g == 0) {
            atomicAdd(&qsi[bh * 64 + e * 8 + j], v);
            atomicAdd(&kso[bh * 64 + e * 8 + j], u);
        }
    }
}

// ---- dots2 vectorized: csk[s]=Q[s]·vq, css[s]=K[s]·vk (no invert, no accum) ----
__global__ void dots_k(const ushort* __restrict__ Q, const ushort* __restrict__ K,
                       const float* __restrict__ vq, const float* __restrict__ vk,
                       float* __restrict__ outq, float* __restrict__ outk) {
    int h = blockIdx.x, b = blockIdx.z;
    int t = threadIdx.x;
    int lane = t & 63, wv = t >> 6;
    int g = lane >> 3, e = lane & 7;
    size_t bh = (size_t)b * NHEAD + h;
    const ushort* qp = Q + (size_t)b * BATSTRIDE + h * 64 + e * 8;
    const ushort* kp = K + (size_t)b * BATSTRIDE + h * 64 + e * 8;
    float4 vq0 = *(const float4*)&vq[bh * 64 + e * 8];
    float4 vq1 = *(const float4*)&vq[bh * 64 + e * 8 + 4];
    float4 vk0 = *(const float4*)&vk[bh * 64 + e * 8];
    float4 vk1 = *(const float4*)&vk[bh * 64 + e * 8 + 4];
    float* oq = outq + bh * S_LEN;
    float* ok = outk + bh * S_LEN;
    int sBase = blockIdx.y * 256 + wv * 64 + g;
    #pragma unroll 2
    for (int i = 0; i < 8; ++i) {
        int s = sBase + i * 8;
        uint4 qr = *(const uint4*)(qp + (size_t)s * DMODEL);
        uint4 kr = *(const uint4*)(kp + (size_t)s * DMODEL);
        float dq = blo(qr.x) * vq0.x + bhi(qr.x) * vq0.y + blo(qr.y) * vq0.z + bhi(qr.y) * vq0.w
                 + blo(qr.z) * vq1.x + bhi(qr.z) * vq1.y + blo(qr.w) * vq1.z + bhi(qr.w) * vq1.w;
        float dk = blo(kr.x) * vk0.x + bhi(kr.x) * vk0.y + blo(kr.y) * vk0.z + bhi(kr.y) * vk0.w
                 + blo(kr.z) * vk1.x + bhi(kr.z) * vk1.y + blo(kr.w) * vk1.z + bhi(kr.w) * vk1.w;
        dq += __shfl_xor(dq, 1); dq += __shfl_xor(dq, 2); dq += __shfl_xor(dq, 4);
        dk += __shfl_xor(dk, 1); dk += __shfl_xor(dk, 2); dk += __shfl_xor(dk, 4);
        if (e == 0) {
            oq[s] = dq;
            ok[s] = dk;
        }
    }
}

// ---- softmax over S per head, batched over b (y); safe in-place (w may == x) ----
__global__ void softmax_k(const float* x, float* w) {
    int h = blockIdx.x;
    int b = blockIdx.y;
    const float* xp = x + ((size_t)b * NHEAD + h) * S_LEN;
    float* wp = w + ((size_t)b * NHEAD + h) * S_LEN;
    float loc[16];
    float mx = -1e30f;
    #pragma unroll
    for (int i = 0; i < 16; ++i) { loc[i] = xp[threadIdx.x + i * 256]; mx = fmaxf(mx, loc[i]); }
    __shared__ float red[256];
    red[threadIdx.x] = mx; __syncthreads();
    for (int st = 128; st; st >>= 1) {
        if (threadIdx.x < st) red[threadIdx.x] = fmaxf(red[threadIdx.x], red[threadIdx.x + st]);
        __syncthreads();
    }
    mx = red[0]; __syncthreads();
    float sm = 0.f;
    #pragma unroll
    for (int i = 0; i < 16; ++i) { loc[i] = __expf(loc[i] - mx); sm += loc[i]; }
    red[threadIdx.x] = sm; __syncthreads();
    for (int st = 128; st; st >>= 1) {
        if (threadIdx.x < st) red[threadIdx.x] += red[threadIdx.x + st];
        __syncthreads();
    }
    float inv = 1.f / red[0];
    #pragma unroll
    for (int i = 0; i < 16; ++i)
        wp[threadIdx.x + i * 256] = loc[i] * inv;
}

// ---- kv[h,k,v] = sum_s (K[s,k]*w[h,s]) * V[s,v], one batch (split-S atomics) ----
__global__ __launch_bounds__(256) void kv_k(const ushort* __restrict__ K,
                                            const ushort* __restrict__ V,
                                            const float* __restrict__ w,
                                            float* __restrict__ kv) {
    int bid = (int)(blockIdx.y * gridDim.x + blockIdx.x);   // gridDim = (16, 32)
    int lid = (bid & 7) * 64 + (bid >> 3);                  // [0,512) bijective
    int h = lid & 15;
    int sy = lid >> 4;                                      // [0,32)
    __shared__ __align__(16) float  KwS[64 * 64];
    __shared__ __align__(16) ushort Vt[64 * 64];
    int t = threadIdx.x;
    int kk = (t & 31) * 2;
    int v0 = (t >> 5) * 8;
    float acc[2][8];
    #pragma unroll
    for (int i = 0; i < 2; ++i)
        #pragma unroll
        for (int j = 0; j < 8; ++j) acc[i][j] = 0.f;
    int sl_s = t >> 2, q = t & 3;
    int sBase = sy * (S_LEN / KV_SPLIT);                    // 128 rows per block
    for (int t0 = 0; t0 < S_LEN / KV_SPLIT; t0 += 64) {
        __syncthreads();
        #pragma unroll
        for (int r = 0; r < 2; ++r) {
            int o = t * 16 + r * 4096;
            int row = o >> 7;
            gld_lds16((char*)Vt + o,
                      V + (size_t)(sBase + t0 + row) * DMODEL + h * 64 + ((o & 127) >> 1));
        }
        {
            int s = sBase + t0 + sl_s;
            float ws = w[(size_t)h * S_LEN + s];
            const ushort* kp = K + (size_t)s * DMODEL + h * 64 + q * 16;
            uint4 ka = *(const uint4*)kp;
            uint4 kb = *(const uint4*)(kp + 8);
            int swz = (sl_s & 7) << 4;
            char* base = (char*)KwS + sl_s * 256;
            f32x4 c0 = { blo(ka.x) * ws, bhi(ka.x) * ws, blo(ka.y) * ws, bhi(ka.y) * ws };
            f32x4 c1 = { blo(ka.z) * ws, bhi(ka.z) * ws, blo(ka.w) * ws, bhi(ka.w) * ws };
            f32x4 c2 = { blo(kb.x) * ws, bhi(kb.x) * ws, blo(kb.y) * ws, bhi(kb.y) * ws };
            f32x4 c3 = { blo(kb.z) * ws, bhi(kb.z) * ws, blo(kb.w) * ws, bhi(kb.w) * ws };
            *(f32x4*)(base + ((q * 64 +  0) ^ swz)) = c0;
            *(f32x4*)(base + ((q * 64 + 16) ^ swz)) = c1;
            *(f32x4*)(base + ((q * 64 + 32) ^ swz)) = c2;
            *(f32x4*)(base + ((q * 64 + 48) ^ swz)) = c3;
        }
        __syncthreads();
        #pragma unroll 2
        for (int sl = 0; sl < 64; ++sl) {
            int swz = (sl & 7) << 4;
            float2 kf = *(const float2*)((const char*)KwS + sl * 256 + ((kk * 4) ^ swz));
            uint4 vv = *(const uint4*)((const char*)Vt + sl * 128 + v0 * 2);
            float vf0 = blo(vv.x), vf1 = bhi(vv.x), vf2 = blo(vv.y), vf3 = bhi(vv.y);
            float vf4 = blo(vv.z), vf5 = bhi(vv.z), vf6 = blo(vv.w), vf7 = bhi(vv.w);
            acc[0][0] += kf.x * vf0; acc[0][1] += kf.x * vf1;
            acc[0][2] += kf.x * vf2; acc[0][3] += kf.x * vf3;
            acc[0][4] += kf.x * vf4; acc[0][5] += kf.x * vf5;
            acc[0][6] += kf.x * vf6; acc[0][7] += kf.x * vf7;
            acc[1][0] += kf.y * vf0; acc[1][1] += kf.y * vf1;
            acc[1][2] += kf.y * vf2; acc[1][3] += kf.y * vf3;
            acc[1][4] += kf.y * vf4; acc[1][5] += kf.y * vf5;
            acc[1][6] += kf.y * vf6; acc[1][7] += kf.y * vf7;
        }
    }
    float* kvp = kv + (size_t)h * 4096;
    #pragma unroll
    for (int i = 0; i < 2; ++i)
        #pragma unroll
        for (int j = 0; j < 8; ++j)
            atomicAdd(&kvp[(kk + i) * 64 + v0 + j], acc[i][j]);
}

// ---- ctx[s,h*64+v] = sig(csink)*si*sum_k Q[s,k]*kv[k,v]; batched over b (z) ----
__global__ __launch_bounds__(256) void ctx_k(const ushort* __restrict__ Qall,
                                             const float* __restrict__ kv4,
                                             const float* __restrict__ siAll,
                                             const float* __restrict__ cskAll,
                                             ushort* __restrict__ ctxAll) {
    int b = (int)blockIdx.z;
    const ushort* Q = Qall + (size_t)b * BATSTRIDE;
    const float* kv = kv4 + (size_t)b * NHEAD * 4096;
    const float* si = siAll + (size_t)b * NHEAD * S_LEN;
    const float* csink = cskAll + (size_t)b * NHEAD * S_LEN;
    ushort* ctx = ctxAll + (size_t)b * BATSTRIDE;

    int bid = (int)(blockIdx.y * gridDim.x + blockIdx.x);   // gridDim = (16, 32)
    int lid = (bid & 7) * 64 + (bid >> 3);                  // [0,512) bijective
    int h = lid & 15;
    int sBlock = (lid >> 4) * 128;
    __shared__ __align__(16) float  kvf[64 * 64];   // [k][v] linear
    __shared__ __align__(16) ushort Qt[64 * 64];    // [s][k] source-preswizzled
    int t = threadIdx.x;
    {
        const float* kp = kv + (size_t)h * 4096;
        #pragma unroll
        for (int i = 0; i < 4; ++i) {
            int idx = t * 4 + i * 1024;
            *(f32x4*)&kvf[idx] = *(const f32x4*)&kp[idx];
        }
    }
    int spair = t >> 3;
    int v0 = (t & 7) * 8;
    for (int tile = 0; tile < 2; ++tile) {
        __syncthreads();
        int sT = sBlock + tile * 64;
        #pragma unroll
        for (int r = 0; r < 2; ++r) {
            int o = t * 16 + r * 4096;
            int row = o >> 7;
            int cb = (o & 127) ^ ((row & 7) << 4);
            gld_lds16((char*)Qt + o, Q + (size_t)(sT + row) * DMODEL + h * 64 + (cb >> 1));
        }
        __syncthreads();
        int s0 = spair * 2, s1 = s0 + 1;
        int swz0 = (s0 & 7) << 4, swz1 = (s1 & 7) << 4;
        float acc0[8], acc1[8];
        #pragma unroll
        for (int j = 0; j < 8; ++j) { acc0[j] = 0.f; acc1[j] = 0.f; }
        #pragma unroll 4
        for (int k = 0; k < 64; k += 4) {
            union { ushort4 v; ushort u[4]; } qa, qb;
            qa.v = *(const ushort4*)((const char*)Qt + s0 * 128 + ((k * 2) ^ swz0));
            qb.v = *(const ushort4*)((const char*)Qt + s1 * 128 + ((k * 2) ^ swz1));
            const char* rbase = (const char*)kvf + k * 256 + v0 * 4;
            #pragma unroll
            for (int kk2 = 0; kk2 < 4; ++kk2) {
                f32x4 r0 = *(const f32x4*)(rbase + kk2 * 256);
                f32x4 r1 = *(const f32x4*)(rbase + kk2 * 256 + 16);
                float qaf = b2f(qa.u[kk2]);
                float qbf = b2f(qb.u[kk2]);
                #pragma unroll
                for (int j = 0; j < 4; ++j) {
                    acc0[j]     += qaf * r0[j];
                    acc0[4 + j] += qaf * r1[j];
                    acc1[j]     += qbf * r0[j];
                    acc1[4 + j] += qbf * r1[j];
                }
            }
        }
        int gs0 = sT + s0, gs1 = sT + s1;
        float sc0 = si[(size_t)h * S_LEN + gs0] * sigmoidf_(csink[(size_t)h * S_LEN + gs0]);
        float sc1 = si[(size_t)h * S_LEN + gs1] * sigmoidf_(csink[(size_t)h * S_LEN + gs1]);
        union { ushort u[8]; uint4 v; } o0, o1;
        #pragma unroll
        for (int j = 0; j < 8; ++j) {
            o0.u[j] = f2b(acc0[j] * sc0);
            o1.u[j] = f2b(acc1[j] * sc1);
        }
        *(uint4*)(ctx + (size_t)gs0 * DMODEL + h * 64 + v0) = o0.v;
        *(uint4*)(ctx + (size_t)gs1 * DMODEL + h * 64 + v0) = o1.v;
    }
}

// ---- LayerNorm(y_bf16 + residual_f32) * gamma + beta -> fp32 out (per-row) ----
__global__ void ln_k(const ushort* __restrict__ y, const float* __restrict__ res,
                     const float* __restrict__ gamma, const float* __restrict__ beta,
                     float* __restrict__ out) {
    size_t row = blockIdx.x;
    const ushort* yp = y + row * DMODEL;
    const float* rp = res + row * DMODEL;
    float x[4];
    float s = 0.f, s2 = 0.f;
    #pragma unroll
    for (int i = 0; i < 4; ++i) {
        int d = threadIdx.x + i * 256;
        x[i] = b2f(yp[d]) + rp[d];
        s += x[i]; s2 += x[i] * x[i];
    }
    __shared__ float r1[256], r2[256];
    r1[threadIdx.x] = s; r2[threadIdx.x] = s2;
    __syncthreads();
    for (int st = 128; st; st >>= 1) {
        if (threadIdx.x < st) { r1[threadIdx.x] += r1[threadIdx.x + st]; r2[threadIdx.x] += r2[threadIdx.x + st]; }
        __syncthreads();
    }
    float mean = r1[0] * (1.f / DMODEL);
    float var = r2[0] * (1.f / DMODEL) - mean * mean;
    float rstd = rsqrtf(var + 1e-5f);
    #pragma unroll
    for (int i = 0; i < 4; ++i) {
        int d = threadIdx.x + i * 256;
        out[row * DMODEL + d] = (x[i] - mean) * rstd * gamma[d] + beta[d];
    }
}

extern "C" void kernel_launch(void* const* d_in, const int* in_sizes, int n_in,
                              void* d_out, int out_size, void* d_ws, size_t ws_size,
                              hipStream_t stream) {
    const float* inQ  = (const float*)d_in[0];
    const float* inK  = (const float*)d_in[1];
    const float* inV  = (const float*)d_in[2];
    const float* WQ   = (const float*)d_in[3];
    const float* WK   = (const float*)d_in[4];
    const float* WV   = (const float*)d_in[5];
    const float* WF   = (const float*)d_in[6];
    const float* gamma= (const float*)d_in[7];
    const float* beta = (const float*)d_in[8];
    float* outf = (float*)d_out;

    // d_out scratch: bf16 Q at [0,32MB), bf16 K/ctx at [32,64MB)
    ushort* Qb  = (ushort*)d_out;
    ushort* KCb = (ushort*)d_out + (size_t)NROWS * DMODEL;

    // d_ws layout (peak 14.06MB, proven R8/R9):
    const size_t MB = 1024ull * 1024ull;
    char* w = (char*)d_ws;
    ushort* Vb  = (ushort*)w;                 // [4096][1024] bf16, 8MB; later O_0 slot
    ushort* Wt  = (ushort*)(w + 8 * MB);      // 2MB weight^T slot (WQ->WK->WV->WF)
    float* si    = (float*)(w + 10 * MB);     // [4][16][4096] f32, 1MB
    float* soCsk = si + 4 * NHEAD * S_LEN;    // 1MB: csk (dots2)
    float* css   = soCsk + 4 * NHEAD * S_LEN; // 1MB: css -> smw (softmax in-place)
    float* Qsum  = css + 4 * NHEAD * S_LEN;   // 4 sum buffers x [4][16][64] = 64KB
    float* Ksum  = Qsum + 4 * NHEAD * 64;
    float* QsI   = Ksum + 4 * NHEAD * 64;
    float* KsO   = QsI  + 4 * NHEAD * 64;
    float* kvb4  = KsO  + 4 * NHEAD * 64;     // [4][16][64][64] f32, 1MB (per-batch)
    size_t sumZeroBytes = 4 * 4 * NHEAD * 64 * sizeof(float);       // 64KB
    size_t kvZeroBytes  = 4ull * NHEAD * 4096 * sizeof(float);      // 1MB

    dim3 tb(32, 8);
    dim3 tg(32, 32);
    dim3 ggFull(DMODEL / 128, NROWS / 128);   // (8, 128)
    dim3 ggB64(DMODEL / 64, BROWS / 64, 1);   // (16, 64) per batch
    dim3 ggP3(DMODEL / 128, BROWS / 128, 4);  // (8, 32, 4) batched P3 gemm128z

    // zero Qsum/Ksum/QsI/KsO before gemm epilogue atomics; all kvb once
    hipMemsetAsync(Qsum, 0, sumZeroBytes, stream);
    hipMemsetAsync(kvb4, 0, kvZeroBytes, stream);

    // Phase 1: Q and K projections (full batch) into d_out; epilogue colsums
    transpose_k<<<tg, tb, 0, stream>>>(WQ, Wt);
    gemm128<1><<<ggFull, 256, 0, stream>>>(inQ, 0, Wt, Qb, 1, Qsum);
    transpose_k<<<tg, tb, 0, stream>>>(WK, Wt);
    gemm128<1><<<ggFull, 256, 0, stream>>>(inK, 0, Wt, KCb, 1, Ksum);
    transpose_k<<<tg, tb, 0, stream>>>(WV, Wt);   // WVt stays through P2

    // Stats: vectorized dots1(+colsum2), dots2, softmax — all 4 batches per launch
    dots1_k<<<dim3(NHEAD, 16, 4), 256, 0, stream>>>(Qb, KCb, Qsum, Ksum, si, QsI, KsO);
    dots_k<<<dim3(NHEAD, 16, 4), 256, 0, stream>>>(Qb, KCb, KsO, QsI, soCsk, css);
    softmax_k<<<dim3(NHEAD, 4), 256, 0, stream>>>(css, css);

    // Phase 2a: per-batch V projection + kv (Vb shared -> serialized pairs)
    for (int b = 0; b < 4; ++b) {
        size_t rowOff = (size_t)b * BATSTRIDE;
        size_t statOff = (size_t)b * NHEAD * S_LEN;
        gemm64<1><<<ggB64, 256, 0, stream>>>(inV, rowOff, Wt, Vb, Vb, 0);
        kv_k<<<dim3(NHEAD, KV_SPLIT), 256, 0, stream>>>(KCb + rowOff, Vb,
                                                        css + statOff,
                                                        kvb4 + (size_t)b * NHEAD * 4096);
    }
    // Phase 2b: batched ctx (all b): reads Qb/kvb4/si/csk, overwrites dead K_b
    ctx_k<<<dim3(NHEAD, KV_SPLIT, 4), 256, 0, stream>>>(Qb, kvb4, si, soCsk, KCb);

    // Phase 3: ONE z-batched gemm128z (ctx @ WF^T), then ln in order 3,2,1,0.
    // O placement: z=0->Vb (dead), z>=1 -> Qb+(z-1)*8MB (Q dead after ctx).
    transpose_k<<<tg, tb, 0, stream>>>(WF, Wt);   // WVt dead now
    gemm128z<<<ggP3, 256, 0, stream>>>(KCb, Wt, Vb, Qb);
    // ln order (clobber-safe, audited R8):
    //   ln3: reads O3=Qb+16MB, writes out[48,64) (ctx2/3 consumed by gemm)
    //   ln2: reads O2=Qb+8MB,  writes out[32,48) (ctx0/1 consumed)
    //   ln1: reads O1=Qb+0,    writes out[16,32) (O3 consumed by ln3)
    //   ln0: reads O0=Vb,      writes out[0,16)  (O1,O2 consumed by ln1,ln2)
    ln_k<<<BROWS, 256, 0, stream>>>(Qb + 2 * BATSTRIDE, inQ + 3 * BATSTRIDE,
                                    gamma, beta, outf + 3 * BATSTRIDE);
    ln_k<<<BROWS, 256, 0, stream>>>(Qb + 1 * BATSTRIDE, inQ + 2 * BATSTRIDE,
                                    gamma, beta, outf + 2 * BATSTRIDE);
    ln_k<<<BROWS, 256, 0, stream>>>(Qb, inQ + 1 * BATSTRIDE,
                                    gamma, beta, outf + 1 * BATSTRIDE);
    ln_k<<<BROWS, 256, 0, stream>>>(Vb, inQ, gamma, beta, outf);
}

// Round 11
// 834.850 us; speedup vs baseline: 1.1313x; 1.0432x over previous
//
#include <hip/hip_runtime.h>
#include <hip/hip_bf16.h>

// FlowAttention: B=4 S=4096 D=1024 H=16 dk=dv=64. Inputs/outputs fp32.
// Round-16: kill the fp32-A tax. R10's top kernel (gemm128<1>, 91us, MfmaUtil 15%)
// pays 12 DMA rounds + 64 cvt/thread/K-step + 48KB LDS for fp32 A. Fix:
//  - cvt_k pre-converts inQ/inK (full) and inV (per batch) to bf16 with the SAME
//    RNE f2b as the old in-gemm cast (bit-identical numerics).
//  - All GEMMs now pure-bf16 and IN-PLACE (A band == C band). Safe per block:
//    all global A reads are in staging (before final barrier); C written only in
//    the epilogue; cross-block bands disjoint. Audited.
//  - gemm128: 32KB LDS, 8 DMA rounds, zero cvt on critical path (m97 structure).
//  - ln_k loads vectorized (uint2/float4).
// Everything else (stats, kv, ctx, gemm128z, phase order) unchanged from R10.
#define S_LEN 4096
#define DMODEL 1024
#define NHEAD 16
#define NROWS 16384      // B*S
#define BROWS 4096       // rows per batch
#define KV_SPLIT 32
#define BATSTRIDE 4194304ull   // elements per batch slice (4096*1024)

typedef __bf16 bf16x8 __attribute__((ext_vector_type(8)));
typedef float  f32x4  __attribute__((ext_vector_type(4)));

__device__ __forceinline__ float b2f(ushort u) {
    union { uint i; float f; } c; c.i = ((uint)u) << 16; return c.f;
}
__device__ __forceinline__ float blo(uint u) {
    union { uint i; float f; } c; c.i = u << 16; return c.f;
}
__device__ __forceinline__ float bhi(uint u) {
    union { uint i; float f; } c; c.i = u & 0xFFFF0000u; return c.f;
}
__device__ __forceinline__ ushort f2b(float f) {
    union { uint i; float f; } c; c.f = f;
    uint r = c.i + 0x7FFF + ((c.i >> 16) & 1);   // round-to-nearest-even
    return (ushort)(r >> 16);
}
__device__ __forceinline__ float sigmoidf_(float x) {
    return 1.f / (1.f + __expf(-x));
}

// async 16B global->LDS DMA. Dest must be thread-linear (base + tid*16).
__device__ __forceinline__ void gld_lds16(void* lds, const void* g) {
    __builtin_amdgcn_global_load_lds(
        (const __attribute__((address_space(1))) uint*)g,
        (__attribute__((address_space(3))) uint*)lds, 16, 0, 0);
}

// ---------------- fp32 -> bf16 (RNE), vectorized grid-stride --------------------
__global__ void cvt_k(const float* __restrict__ in, ushort* __restrict__ out, int n8) {
    int idx = blockIdx.x * blockDim.x + threadIdx.x;
    int stride = gridDim.x * blockDim.x;
    for (int i = idx; i < n8; i += stride) {
        float4 a = *(const float4*)(in + (size_t)i * 8);
        float4 b = *(const float4*)(in + (size_t)i * 8 + 4);
        union { ushort u[8]; uint4 v; } o;
        o.u[0] = f2b(a.x); o.u[1] = f2b(a.y); o.u[2] = f2b(a.z); o.u[3] = f2b(a.w);
        o.u[4] = f2b(b.x); o.u[5] = f2b(b.y); o.u[6] = f2b(b.z); o.u[7] = f2b(b.w);
        *(uint4*)(out + (size_t)i * 8) = o.v;
    }
}

// ---------------- transpose 1024x1024: out[n][k] = bf16(in[k][n]), in fp32 ------
__global__ void transpose_k(const float* __restrict__ in, ushort* __restrict__ out) {
    __shared__ ushort tile[32][33];
    int x = blockIdx.x * 32 + threadIdx.x;
    int y0 = blockIdx.y * 32;
    for (int i = threadIdx.y; i < 32; i += 8)
        tile[i][threadIdx.x] = f2b(in[(size_t)(y0 + i) * DMODEL + x]);
    __syncthreads();
    int xo = blockIdx.y * 32 + threadIdx.x;
    int yo0 = blockIdx.x * 32;
    for (int i = threadIdx.y; i < 32; i += 8)
        out[(size_t)(yo0 + i) * DMODEL + xo] = tile[threadIdx.x][i];
}

// ---------------- MFMA GEMM 128x128, bf16 A (in-place capable) ------------------
// m97 structure: 128x128 tile, 4 waves 2x2, 4x4 frags of mfma 16x16x32 bf16,
// BK=64, 2 barriers/iter, gld_lds staging, 32KB LDS.
// Swizzle byte_in_row ^= (row&7)<<4: inverse on GLOBAL source + on LDS read;
// DMA dest linear (rule #21). XCD swizzle: lid=(bid&7)*(nwg/8)+bid/8.
// In-place (A==C) is safe: all global A reads in staging, C in epilogue only.
// csum != nullptr: epilogue per-column sums of stored output into csum[b][h][64].
__global__ __launch_bounds__(256) void gemm128(const ushort* __restrict__ A,
                                               const ushort* __restrict__ Bt,
                                               ushort* __restrict__ C, int act,
                                               float* __restrict__ csum) {
    __shared__ __align__(16) char smem[32768];
    char* smA = smem + 16384;

    int nwg = (int)(gridDim.x * gridDim.y);
    int bid = (int)(blockIdx.y * gridDim.x + blockIdx.x);
    int lid = (bid & 7) * (nwg >> 3) + (bid >> 3);
    int n0 = (lid & 7) * 128;                     // gridDim.x == 8
    int m0 = (lid >> 3) * 128;

    int t = threadIdx.x;
    int lane = t & 63, wave = t >> 6;
    int wm = (wave >> 1) * 64, wn = (wave & 1) * 64;
    int fr = lane & 15;            // frag row (A) / col (B)
    int kq = (lane >> 4) * 8;      // k offset within 32-step

    int ldsOff[4], rowOf[4], bcB[4];
    #pragma unroll
    for (int r = 0; r < 4; ++r) {
        int o = t * 16 + r * 4096;
        int row = o >> 7;
        ldsOff[r] = o;
        rowOf[r] = row;
        bcB[r] = (o & 127) ^ ((row & 7) << 4);
    }

    f32x4 acc[4][4];
    #pragma unroll
    for (int i = 0; i < 4; ++i)
        #pragma unroll
        for (int j = 0; j < 4; ++j) acc[i][j] = (f32x4){0.f, 0.f, 0.f, 0.f};

    for (int k0 = 0; k0 < DMODEL; k0 += 64) {
        __syncthreads();   // prev iteration's LDS reads done before overwrite
        #pragma unroll
        for (int r = 0; r < 4; ++r)
            gld_lds16(smem + ldsOff[r],
                      Bt + (size_t)(n0 + rowOf[r]) * DMODEL + k0 + (bcB[r] >> 1));
        #pragma unroll
        for (int r = 0; r < 4; ++r)
            gld_lds16(smA + ldsOff[r],
                      A + (size_t)(m0 + rowOf[r]) * DMODEL + k0 + (bcB[r] >> 1));
        __syncthreads();   // vmcnt(0) drain before barrier

        #pragma unroll
        for (int h = 0; h < 2; ++h) {
            bf16x8 av[4], bv[4];
            #pragma unroll
            for (int i = 0; i < 4; ++i) {
                int row = wm + i * 16 + fr;
                int k = h * 32 + kq;
                int o = ((row << 7) + (k << 1)) ^ ((row & 7) << 4);
                av[i] = *(const bf16x8*)(smA + o);
            }
            #pragma unroll
            for (int j = 0; j < 4; ++j) {
                int nrow = wn + j * 16 + fr;
                int k = h * 32 + kq;
                int o = ((nrow << 7) + (k << 1)) ^ ((nrow & 7) << 4);
                bv[j] = *(const bf16x8*)(smem + o);
            }
            #pragma unroll
            for (int i = 0; i < 4; ++i)
                #pragma unroll
                for (int j = 0; j < 4; ++j)
                    acc[i][j] = __builtin_amdgcn_mfma_f32_16x16x32_bf16(av[i], bv[j], acc[i][j], 0, 0, 0);
        }
    }

    int rbase = (lane >> 4) * 4;
    int cix = lane & 15;
    float colacc[4] = {0.f, 0.f, 0.f, 0.f};
    #pragma unroll
    for (int i = 0; i < 4; ++i)
        #pragma unroll
        for (int j = 0; j < 4; ++j) {
            int col = n0 + wn + j * 16 + cix;
            #pragma unroll
            for (int r = 0; r < 4; ++r) {
                int row = m0 + wm + i * 16 + rbase + r;
                float v = acc[i][j][r];
                if (act) v = sigmoidf_(v);
                ushort ub = f2b(v);
                C[(size_t)row * DMODEL + col] = ub;
                if (csum) colacc[j] += b2f(ub);
            }
        }
    if (csum) {
        __syncthreads();
        float* cred = (float*)smem;     // [2][128]
        cred[t] = 0.f;
        __syncthreads();
        #pragma unroll
        for (int j = 0; j < 4; ++j) {
            float s = colacc[j];
            s += __shfl_xor(s, 16);
            s += __shfl_xor(s, 32);
            if (lane < 16) cred[(wm >> 6) * 128 + wn + j * 16 + lane] = s;
        }
        __syncthreads();
        if (t < 128) {
            float tot = cred[t] + cred[128 + t];
            int col = n0 + t;
            int b = m0 >> 12;
            atomicAdd(&csum[((size_t)b * NHEAD + (col >> 6)) * 64 + (col & 63)], tot);
        }
    }
}

// ---------------- MFMA GEMM 128x128, bf16 A, z-batched (P3) ---------------------
__global__ __launch_bounds__(256) void gemm128z(const ushort* __restrict__ A,
                                                const ushort* __restrict__ Bt,
                                                ushort* __restrict__ C0,
                                                ushort* __restrict__ C1) {
    __shared__ __align__(16) char smem[32768];
    char* smA = smem + 16384;

    int z = (int)blockIdx.z;
    const ushort* Ab = A + (size_t)z * BATSTRIDE;
    ushort* C = z ? C1 + (size_t)(z - 1) * BATSTRIDE : C0;

    int nwg = (int)(gridDim.x * gridDim.y);       // 256 per slice
    int bid = (int)(blockIdx.y * gridDim.x + blockIdx.x);
    int lid = (bid & 7) * (nwg >> 3) + (bid >> 3);
    int n0 = (lid & 7) * 128;
    int m0 = (lid >> 3) * 128;                    // [0, 4096)

    int t = threadIdx.x;
    int lane = t & 63, wave = t >> 6;
    int wm = (wave >> 1) * 64, wn = (wave & 1) * 64;
    int fr = lane & 15;
    int kq = (lane >> 4) * 8;

    int ldsOff[4], rowOf[4], bcB[4];
    #pragma unroll
    for (int r = 0; r < 4; ++r) {
        int o = t * 16 + r * 4096;
        int row = o >> 7;
        ldsOff[r] = o;
        rowOf[r] = row;
        bcB[r] = (o & 127) ^ ((row & 7) << 4);
    }

    f32x4 acc[4][4];
    #pragma unroll
    for (int i = 0; i < 4; ++i)
        #pragma unroll
        for (int j = 0; j < 4; ++j) acc[i][j] = (f32x4){0.f, 0.f, 0.f, 0.f};

    for (int k0 = 0; k0 < DMODEL; k0 += 64) {
        __syncthreads();
        #pragma unroll
        for (int r = 0; r < 4; ++r)
            gld_lds16(smem + ldsOff[r],
                      Bt + (size_t)(n0 + rowOf[r]) * DMODEL + k0 + (bcB[r] >> 1));
        #pragma unroll
        for (int r = 0; r < 4; ++r)
            gld_lds16(smA + ldsOff[r],
                      Ab + (size_t)(m0 + rowOf[r]) * DMODEL + k0 + (bcB[r] >> 1));
        __syncthreads();

        #pragma unroll
        for (int h = 0; h < 2; ++h) {
            bf16x8 av[4], bv[4];
            #pragma unroll
            for (int i = 0; i < 4; ++i) {
                int row = wm + i * 16 + fr;
                int k = h * 32 + kq;
                int o = ((row << 7) + (k << 1)) ^ ((row & 7) << 4);
                av[i] = *(const bf16x8*)(smA + o);
            }
            #pragma unroll
            for (int j = 0; j < 4; ++j) {
                int nrow = wn + j * 16 + fr;
                int k = h * 32 + kq;
                int o = ((nrow << 7) + (k << 1)) ^ ((nrow & 7) << 4);
                bv[j] = *(const bf16x8*)(smem + o);
            }
            #pragma unroll
            for (int i = 0; i < 4; ++i)
                #pragma unroll
                for (int j = 0; j < 4; ++j)
                    acc[i][j] = __builtin_amdgcn_mfma_f32_16x16x32_bf16(av[i], bv[j], acc[i][j], 0, 0, 0);
        }
    }

    int rbase = (lane >> 4) * 4;
    int cix = lane & 15;
    #pragma unroll
    for (int i = 0; i < 4; ++i)
        #pragma unroll
        for (int j = 0; j < 4; ++j) {
            int col = n0 + wn + j * 16 + cix;
            #pragma unroll
            for (int r = 0; r < 4; ++r) {
                int row = m0 + wm + i * 16 + rbase + r;
                C[(size_t)row * DMODEL + col] = f2b(acc[i][j][r]);
            }
        }
}

// ---------------- MFMA GEMM 64x64, bf16 A (per-batch V-proj, in-place) ----------
__global__ __launch_bounds__(256) void gemm64(const ushort* __restrict__ A,
                                              const ushort* __restrict__ Bt,
                                              ushort* __restrict__ C, int act) {
    __shared__ __align__(16) char smem[16384];
    char* smA = smem + 8192;

    int nwg = (int)(gridDim.x * gridDim.y);                  // 1024
    int bid = (int)(blockIdx.y * gridDim.x + blockIdx.x);
    int lid = (bid & 7) * (nwg >> 3) + (bid >> 3);
    int n0 = (lid & 15) * 64;                                // gridDim.x == 16
    int m0 = (lid >> 4) * 64;

    int t = threadIdx.x;
    int lane = t & 63, wave = t >> 6;
    int wm = (wave >> 1) * 32, wn = (wave & 1) * 32;
    int fr = lane & 15;
    int kq = (lane >> 4) * 8;

    f32x4 acc[2][2];
    #pragma unroll
    for (int i = 0; i < 2; ++i)
        #pragma unroll
        for (int j = 0; j < 2; ++j) acc[i][j] = (f32x4){0.f, 0.f, 0.f, 0.f};

    for (int k0 = 0; k0 < DMODEL; k0 += 64) {
        __syncthreads();
        #pragma unroll
        for (int r = 0; r < 2; ++r) {
            int o = t * 16 + r * 4096;
            int row = o >> 7;
            int cb = (o & 127) ^ ((row & 7) << 4);
            gld_lds16(smem + o, Bt + (size_t)(n0 + row) * DMODEL + k0 + (cb >> 1));
        }
        #pragma unroll
        for (int r = 0; r < 2; ++r) {
            int o = t * 16 + r * 4096;
            int row = o >> 7;
            int cb = (o & 127) ^ ((row & 7) << 4);
            gld_lds16(smA + o, A + (size_t)(m0 + row) * DMODEL + k0 + (cb >> 1));
        }
        __syncthreads();   // vmcnt(0) drain

        #pragma unroll
        for (int h = 0; h < 2; ++h) {
            bf16x8 av[2], bv[2];
            #pragma unroll
            for (int i = 0; i < 2; ++i) {
                int row = wm + i * 16 + fr;
                int k = h * 32 + kq;
                int o = ((row << 7) + (k << 1)) ^ ((row & 7) << 4);
                av[i] = *(const bf16x8*)(smA + o);
            }
            #pragma unroll
            for (int j = 0; j < 2; ++j) {
                int nrow = wn + j * 16 + fr;
                int k = h * 32 + kq;
                int o = ((nrow << 7) + (k << 1)) ^ ((nrow & 7) << 4);
                bv[j] = *(const bf16x8*)(smem + o);
            }
            #pragma unroll
            for (int i = 0; i < 2; ++i)
                #pragma unroll
                for (int j = 0; j < 2; ++j)
                    acc[i][j] = __builtin_amdgcn_mfma_f32_16x16x32_bf16(av[i], bv[j], acc[i][j], 0, 0, 0);
        }
    }

    int rbase = (lane >> 4) * 4;
    int cix = lane & 15;
    #pragma unroll
    for (int i = 0; i < 2; ++i)
        #pragma unroll
        for (int j = 0; j < 2; ++j) {
            int col = n0 + wn + j * 16 + cix;
            #pragma unroll
            for (int r = 0; r < 4; ++r) {
                int row = m0 + wm + i * 16 + rbase + r;
                float v = acc[i][j][r];
                if (act) v = sigmoidf_(v);
                C[(size_t)row * DMODEL + col] = f2b(v);
            }
        }
}

// ---- fused dots1 + weighted colsum2, vectorized (8 lanes per s) ----
__global__ void dots1_k(const ushort* __restrict__ Q, const ushort* __restrict__ K,
                        const float* __restrict__ Qsum, const float* __restrict__ Ksum,
                        float* __restrict__ si_out, float* __restrict__ qsi,
                        float* __restrict__ kso) {
    int h = blockIdx.x, b = blockIdx.z;
    int t = threadIdx.x;
    int lane = t & 63, wv = t >> 6;
    int g = lane >> 3, e = lane & 7;
    size_t bh = (size_t)b * NHEAD + h;
    const ushort* qp = Q + (size_t)b * BATSTRIDE + h * 64 + e * 8;
    const ushort* kp = K + (size_t)b * BATSTRIDE + h * 64 + e * 8;
    float4 vq0 = *(const float4*)&Ksum[bh * 64 + e * 8];
    float4 vq1 = *(const float4*)&Ksum[bh * 64 + e * 8 + 4];
    float4 vk0 = *(const float4*)&Qsum[bh * 64 + e * 8];
    float4 vk1 = *(const float4*)&Qsum[bh * 64 + e * 8 + 4];
    float* sip = si_out + bh * S_LEN;
    int sBase = blockIdx.y * 256 + wv * 64 + g;
    float aq[8], ak[8];
    #pragma unroll
    for (int j = 0; j < 8; ++j) { aq[j] = 0.f; ak[j] = 0.f; }
    #pragma unroll 2
    for (int i = 0; i < 8; ++i) {
        int s = sBase + i * 8;
        uint4 qr = *(const uint4*)(qp + (size_t)s * DMODEL);
        uint4 kr = *(const uint4*)(kp + (size_t)s * DMODEL);
        float qf[8] = { blo(qr.x), bhi(qr.x), blo(qr.y), bhi(qr.y),
                        blo(qr.z), bhi(qr.z), blo(qr.w), bhi(qr.w) };
        float kf[8] = { blo(kr.x), bhi(kr.x), blo(kr.y), bhi(kr.y),
                        blo(kr.z), bhi(kr.z), blo(kr.w), bhi(kr.w) };
        float dq = qf[0] * vq0.x + qf[1] * vq0.y + qf[2] * vq0.z + qf[3] * vq0.w
                 + qf[4] * vq1.x + qf[5] * vq1.y + qf[6] * vq1.z + qf[7] * vq1.w;
        float dk = kf[0] * vk0.x + kf[1] * vk0.y + kf[2] * vk0.z + kf[3] * vk0.w
                 + kf[4] * vk1.x + kf[5] * vk1.y + kf[6] * vk1.z + kf[7] * vk1.w;
        dq += __shfl_xor(dq, 1); dq += __shfl_xor(dq, 2); dq += __shfl_xor(dq, 4);
        dk += __shfl_xor(dk, 1); dk += __shfl_xor(dk, 2); dk += __shfl_xor(dk, 4);
        float si_ = 1.f / dq, so_ = 1.f / dk;
        if (e == 0) sip[s] = si_;
        #pragma unroll
        for (int j = 0; j < 8; ++j) {
            aq[j] += qf[j] * si_;
            ak[j] += kf[j] * so_;
        }
    }
    #pragma unroll
    for (int j = 0; j < 8; ++j) {
        float v = aq[j];
        v += __shfl_xor(v, 8); v += __shfl_xor(v, 16); v += __shfl_xor(v, 32);
        float u = ak[j];
        u += __shfl_xor(u, 8); u += __shfl_xor(u, 16); u += __shfl_xor(u, 32);
        if (g == 0) {
            atomicAdd(&qsi[bh * 64 + e * 8 + j], v);
            atomicAdd(&kso[bh * 64 + e * 8 + j], u);
        }
    }
}

// ---- dots2 vectorized: csk[s]=Q[s]·vq, css[s]=K[s]·vk ----
__global__ void dots_k(const ushort* __restrict__ Q, const ushort* __restrict__ K,
                       const float* __restrict__ vq, const float* __restrict__ vk,
                       float* __restrict__ outq, float* __restrict__ outk) {
    int h = blockIdx.x, b = blockIdx.z;
    int t = threadIdx.x;
    int lane = t & 63, wv = t >> 6;
    int g = lane >> 3, e = lane & 7;
    size_t bh = (size_t)b * NHEAD + h;
    const ushort* qp = Q + (size_t)b * BATSTRIDE + h * 64 + e * 8;
    const ushort* kp = K + (size_t)b * BATSTRIDE + h * 64 + e * 8;
    float4 vq0 = *(const float4*)&vq[bh * 64 + e * 8];
    float4 vq1 = *(const float4*)&vq[bh * 64 + e * 8 + 4];
    float4 vk0 = *(const float4*)&vk[bh * 64 + e * 8];
    float4 vk1 = *(const float4*)&vk[bh * 64 + e * 8 + 4];
    float* oq = outq + bh * S_LEN;
    float* ok = outk + bh * S_LEN;
    int sBase = blockIdx.y * 256 + wv * 64 + g;
    #pragma unroll 2
    for (int i = 0; i < 8; ++i) {
        int s = sBase + i * 8;
        uint4 qr = *(const uint4*)(qp + (size_t)s * DMODEL);
        uint4 kr = *(const uint4*)(kp + (size_t)s * DMODEL);
        float dq = blo(qr.x) * vq0.x + bhi(qr.x) * vq0.y + blo(qr.y) * vq0.z + bhi(qr.y) * vq0.w
                 + blo(qr.z) * vq1.x + bhi(qr.z) * vq1.y + blo(qr.w) * vq1.z + bhi(qr.w) * vq1.w;
        float dk = blo(kr.x) * vk0.x + bhi(kr.x) * vk0.y + blo(kr.y) * vk0.z + bhi(kr.y) * vk0.w
                 + blo(kr.z) * vk1.x + bhi(kr.z) * vk1.y + blo(kr.w) * vk1.z + bhi(kr.w) * vk1.w;
        dq += __shfl_xor(dq, 1); dq += __shfl_xor(dq, 2); dq += __shfl_xor(dq, 4);
        dk += __shfl_xor(dk, 1); dk += __shfl_xor(dk, 2); dk += __shfl_xor(dk, 4);
        if (e == 0) {
            oq[s] = dq;
            ok[s] = dk;
        }
    }
}

// ---- softmax over S per head, batched over b (y); safe in-place ----
__global__ void softmax_k(const float* x, float* w) {
    int h = blockIdx.x;
    int b = blockIdx.y;
    const float* xp = x + ((size_t)b * NHEAD + h) * S_LEN;
    float* wp = w + ((size_t)b * NHEAD + h) * S_LEN;
    float loc[16];
    float mx = -1e30f;
    #pragma unroll
    for (int i = 0; i < 16; ++i) { loc[i] = xp[threadIdx.x + i * 256]; mx = fmaxf(mx, loc[i]); }
    __shared__ float red[256];
    red[threadIdx.x] = mx; __syncthreads();
    for (int st = 128; st; st >>= 1) {
        if (threadIdx.x < st) red[threadIdx.x] = fmaxf(red[threadIdx.x], red[threadIdx.x + st]);
        __syncthreads();
    }
    mx = red[0]; __syncthreads();
    float sm = 0.f;
    #pragma unroll
    for (int i = 0; i < 16; ++i) { loc[i] = __expf(loc[i] - mx); sm += loc[i]; }
    red[threadIdx.x] = sm; __syncthreads();
    for (int st = 128; st; st >>= 1) {
        if (threadIdx.x < st) red[threadIdx.x] += red[threadIdx.x + st];
        __syncthreads();
    }
    float inv = 1.f / red[0];
    #pragma unroll
    for (int i = 0; i < 16; ++i)
        wp[threadIdx.x + i * 256] = loc[i] * inv;
}

// ---- kv[h,k,v] = sum_s (K[s,k]*w[h,s]) * V[s,v], one batch (split-S atomics) ----
__global__ __launch_bounds__(256) void kv_k(const ushort* __restrict__ K,
                                            const ushort* __restrict__ V,
                                            const float* __restrict__ w,
                                            float* __restrict__ kv) {
    int bid = (int)(blockIdx.y * gridDim.x + blockIdx.x);   // gridDim = (16, 32)
    int lid = (bid & 7) * 64 + (bid >> 3);                  // [0,512) bijective
    int h = lid & 15;
    int sy = lid >> 4;                                      // [0,32)
    __shared__ __align__(16) float  KwS[64 * 64];
    __shared__ __align__(16) ushort Vt[64 * 64];
    int t = threadIdx.x;
    int kk = (t & 31) * 2;
    int v0 = (t >> 5) * 8;
    float acc[2][8];
    #pragma unroll
    for (int i = 0; i < 2; ++i)
        #pragma unroll
        for (int j = 0; j < 8; ++j) acc[i][j] = 0.f;
    int sl_s = t >> 2, q = t & 3;
    int sBase = sy * (S_LEN / KV_SPLIT);                    // 128 rows per block
    for (int t0 = 0; t0 < S_LEN / KV_SPLIT; t0 += 64) {
        __syncthreads();
        #pragma unroll
        for (int r = 0; r < 2; ++r) {
            int o = t * 16 + r * 4096;
            int row = o >> 7;
            gld_lds16((char*)Vt + o,
                      V + (size_t)(sBase + t0 + row) * DMODEL + h * 64 + ((o & 127) >> 1));
        }
        {
            int s = sBase + t0 + sl_s;
            float ws = w[(size_t)h * S_LEN + s];
            const ushort* kp = K + (size_t)s * DMODEL + h * 64 + q * 16;
            uint4 ka = *(const uint4*)kp;
            uint4 kb = *(const uint4*)(kp + 8);
            int swz = (sl_s & 7) << 4;
            char* base = (char*)KwS + sl_s * 256;
            f32x4 c0 = { blo(ka.x) * ws, bhi(ka.x) * ws, blo(ka.y) * ws, bhi(ka.y) * ws };
            f32x4 c1 = { blo(ka.z) * ws, bhi(ka.z) * ws, blo(ka.w) * ws, bhi(ka.w) * ws };
            f32x4 c2 = { blo(kb.x) * ws, bhi(kb.x) * ws, blo(kb.y) * ws, bhi(kb.y) * ws };
            f32x4 c3 = { blo(kb.z) * ws, bhi(kb.z) * ws, blo(kb.w) * ws, bhi(kb.w) * ws };
            *(f32x4*)(base + ((q * 64 +  0) ^ swz)) = c0;
            *(f32x4*)(base + ((q * 64 + 16) ^ swz)) = c1;
            *(f32x4*)(base + ((q * 64 + 32) ^ swz)) = c2;
            *(f32x4*)(base + ((q * 64 + 48) ^ swz)) = c3;
        }
        __syncthreads();
        #pragma unroll 2
        for (int sl = 0; sl < 64; ++sl) {
            int swz = (sl & 7) << 4;
            float2 kf = *(const float2*)((const char*)KwS + sl * 256 + ((kk * 4) ^ swz));
            uint4 vv = *(const uint4*)((const char*)Vt + sl * 128 + v0 * 2);
            float vf0 = blo(vv.x), vf1 = bhi(vv.x), vf2 = blo(vv.y), vf3 = bhi(vv.y);
            float vf4 = blo(vv.z), vf5 = bhi(vv.z), vf6 = blo(vv.w), vf7 = bhi(vv.w);
            acc[0][0] += kf.x * vf0; acc[0][1] += kf.x * vf1;
            acc[0][2] += kf.x * vf2; acc[0][3] += kf.x * vf3;
            acc[0][4] += kf.x * vf4; acc[0][5] += kf.x * vf5;
            acc[0][6] += kf.x * vf6; acc[0][7] += kf.x * vf7;
            acc[1][0] += kf.y * vf0; acc[1][1] += kf.y * vf1;
            acc[1][2] += kf.y * vf2; acc[1][3] += kf.y * vf3;
            acc[1][4] += kf.y * vf4; acc[1][5] += kf.y * vf5;
            acc[1][6] += kf.y * vf6; acc[1][7] += kf.y * vf7;
        }
    }
    float* kvp = kv + (size_t)h * 4096;
    #pragma unroll
    for (int i = 0; i < 2; ++i)
        #pragma unroll
        for (int j = 0; j < 8; ++j)
            atomicAdd(&kvp[(kk + i) * 64 + v0 + j], acc[i][j]);
}

// ---- ctx[s,h*64+v] = sig(csink)*si*sum_k Q[s,k]*kv[k,v]; batched over b (z) ----
__global__ __launch_bounds__(256) void ctx_k(const ushort* __restrict__ Qall,
                                             const float* __restrict__ kv4,
                                             const float* __restrict__ siAll,
                                             const float* __restrict__ cskAll,
                                             ushort* __restrict__ ctxAll) {
    int b = (int)blockIdx.z;
    const ushort* Q = Qall + (size_t)b * BATSTRIDE;
    const float* kv = kv4 + (size_t)b * NHEAD * 4096;
    const float* si = siAll + (size_t)b * NHEAD * S_LEN;
    const float* csink = cskAll + (size_t)b * NHEAD * S_LEN;
    ushort* ctx = ctxAll + (size_t)b * BATSTRIDE;

    int bid = (int)(blockIdx.y * gridDim.x + blockIdx.x);   // gridDim = (16, 32)
    int lid = (bid & 7) * 64 + (bid >> 3);                  // [0,512) bijective
    int h = lid & 15;
    int sBlock = (lid >> 4) * 128;
    __shared__ __align__(16) float  kvf[64 * 64];   // [k][v] linear
    __shared__ __align__(16) ushort Qt[64 * 64];    // [s][k] source-preswizzled
    int t = threadIdx.x;
    {
        const float* kp = kv + (size_t)h * 4096;
        #pragma unroll
        for (int i = 0; i < 4; ++i) {
            int idx = t * 4 + i * 1024;
            *(f32x4*)&kvf[idx] = *(const f32x4*)&kp[idx];
        }
    }
    int spair = t >> 3;
    int v0 = (t & 7) * 8;
    for (int tile = 0; tile < 2; ++tile) {
        __syncthreads();
        int sT = sBlock + tile * 64;
        #pragma unroll
        for (int r = 0; r < 2; ++r) {
            int o = t * 16 + r * 4096;
            int row = o >> 7;
            int cb = (o & 127) ^ ((row & 7) << 4);
            gld_lds16((char*)Qt + o, Q + (size_t)(sT + row) * DMODEL + h * 64 + (cb >> 1));
        }
        __syncthreads();
        int s0 = spair * 2, s1 = s0 + 1;
        int swz0 = (s0 & 7) << 4, swz1 = (s1 & 7) << 4;
        float acc0[8], acc1[8];
        #pragma unroll
        for (int j = 0; j < 8; ++j) { acc0[j] = 0.f; acc1[j] = 0.f; }
        #pragma unroll 4
        for (int k = 0; k < 64; k += 4) {
            union { ushort4 v; ushort u[4]; } qa, qb;
            qa.v = *(const ushort4*)((const char*)Qt + s0 * 128 + ((k * 2) ^ swz0));
            qb.v = *(const ushort4*)((const char*)Qt + s1 * 128 + ((k * 2) ^ swz1));
            const char* rbase = (const char*)kvf + k * 256 + v0 * 4;
            #pragma unroll
            for (int kk2 = 0; kk2 < 4; ++kk2) {
                f32x4 r0 = *(const f32x4*)(rbase + kk2 * 256);
                f32x4 r1 = *(const f32x4*)(rbase + kk2 * 256 + 16);
                float qaf = b2f(qa.u[kk2]);
                float qbf = b2f(qb.u[kk2]);
                #pragma unroll
                for (int j = 0; j < 4; ++j) {
                    acc0[j]     += qaf * r0[j];
                    acc0[4 + j] += qaf * r1[j];
                    acc1[j]     += qbf * r0[j];
                    acc1[4 + j] += qbf * r1[j];
                }
            }
        }
        int gs0 = sT + s0, gs1 = sT + s1;
        float sc0 = si[(size_t)h * S_LEN + gs0] * sigmoidf_(csink[(size_t)h * S_LEN + gs0]);
        float sc1 = si[(size_t)h * S_LEN + gs1] * sigmoidf_(csink[(size_t)h * S_LEN + gs1]);
        union { ushort u[8]; uint4 v; } o0, o1;
        #pragma unroll
        for (int j = 0; j < 8; ++j) {
            o0.u[j] = f2b(acc0[j] * sc0);
            o1.u[j] = f2b(acc1[j] * sc1);
        }
        *(uint4*)(ctx + (size_t)gs0 * DMODEL + h * 64 + v0) = o0.v;
        *(uint4*)(ctx + (size_t)gs1 * DMODEL + h * 64 + v0) = o1.v;
    }
}

// ---- LayerNorm(y_bf16 + residual_f32) * gamma + beta -> fp32 out (per-row) ----
// Vectorized: thread covers 4 contiguous dims (uint2 y, float4 res/out).
__global__ void ln_k(const ushort* __restrict__ y, const float* __restrict__ res,
                     const float* __restrict__ gamma, const float* __restrict__ beta,
                     float* __restrict__ out) {
    size_t row = blockIdx.x;
    int d0 = threadIdx.x * 4;
    const ushort* yp = y + row * DMODEL;
    const float* rp = res + row * DMODEL;
    uint2 yv = *(const uint2*)(yp + d0);
    float4 rv = *(const float4*)(rp + d0);
    float x0 = blo(yv.x) + rv.x, x1 = bhi(yv.x) + rv.y;
    float x2 = blo(yv.y) + rv.z, x3 = bhi(yv.y) + rv.w;
    float s = x0 + x1 + x2 + x3;
    float s2 = x0 * x0 + x1 * x1 + x2 * x2 + x3 * x3;
    __shared__ float r1[256], r2[256];
    r1[threadIdx.x] = s; r2[threadIdx.x] = s2;
    __syncthreads();
    for (int st = 128; st; st >>= 1) {
        if (threadIdx.x < st) { r1[threadIdx.x] += r1[threadIdx.x + st]; r2[threadIdx.x] += r2[threadIdx.x + st]; }
        __syncthreads();
    }
    float mean = r1[0] * (1.f / DMODEL);
    float var = r2[0] * (1.f / DMODEL) - mean * mean;
    float rstd = rsqrtf(var + 1e-5f);
    float4 gv = *(const float4*)(gamma + d0);
    float4 bv = *(const float4*)(beta + d0);
    float4 ov;
    ov.x = (x0 - mean) * rstd * gv.x + bv.x;
    ov.y = (x1 - mean) * rstd * gv.y + bv.y;
    ov.z = (x2 - mean) * rstd * gv.z + bv.z;
    ov.w = (x3 - mean) * rstd * gv.w + bv.w;
    *(float4*)(out + row * DMODEL + d0) = ov;
}

extern "C" void kernel_launch(void* const* d_in, const int* in_sizes, int n_in,
                              void* d_out, int out_size, void* d_ws, size_t ws_size,
                              hipStream_t stream) {
    const float* inQ  = (const float*)d_in[0];
    const float* inK  = (const float*)d_in[1];
    const float* inV  = (const float*)d_in[2];
    const float* WQ   = (const float*)d_in[3];
    const float* WK   = (const float*)d_in[4];
    const float* WV   = (const float*)d_in[5];
    const float* WF   = (const float*)d_in[6];
    const float* gamma= (const float*)d_in[7];
    const float* beta = (const float*)d_in[8];
    float* outf = (float*)d_out;

    // d_out scratch: bf16 Q at [0,32MB), bf16 K/ctx at [32,64MB)
    ushort* Qb  = (ushort*)d_out;
    ushort* KCb = (ushort*)d_out + (size_t)NROWS * DMODEL;

    // d_ws layout (peak 14.06MB, proven R8-R10):
    const size_t MB = 1024ull * 1024ull;
    char* w = (char*)d_ws;
    ushort* Vb  = (ushort*)w;                 // [4096][1024] bf16, 8MB; later O_0 slot
    ushort* Wt  = (ushort*)(w + 8 * MB);      // 2MB weight^T slot (WQ->WK->WV->WF)
    float* si    = (float*)(w + 10 * MB);     // [4][16][4096] f32, 1MB
    float* soCsk = si + 4 * NHEAD * S_LEN;    // 1MB: csk (dots2)
    float* css   = soCsk + 4 * NHEAD * S_LEN; // 1MB: css -> smw (softmax in-place)
    float* Qsum  = css + 4 * NHEAD * S_LEN;   // 4 sum buffers x [4][16][64] = 64KB
    float* Ksum  = Qsum + 4 * NHEAD * 64;
    float* QsI   = Ksum + 4 * NHEAD * 64;
    float* KsO   = QsI  + 4 * NHEAD * 64;
    float* kvb4  = KsO  + 4 * NHEAD * 64;     // [4][16][64][64] f32, 1MB (per-batch)
    size_t sumZeroBytes = 4 * 4 * NHEAD * 64 * sizeof(float);       // 64KB
    size_t kvZeroBytes  = 4ull * NHEAD * 4096 * sizeof(float);      // 1MB

    dim3 tb(32, 8);
    dim3 tg(32, 32);
    dim3 ggFull(DMODEL / 128, NROWS / 128);   // (8, 128)
    dim3 ggB64(DMODEL / 64, BROWS / 64);      // (16, 64) per batch
    dim3 ggP3(DMODEL / 128, BROWS / 128, 4);  // (8, 32, 4) batched P3 gemm128z

    // zero Qsum/Ksum/QsI/KsO before gemm epilogue atomics; all kvb once
    hipMemsetAsync(Qsum, 0, sumZeroBytes, stream);
    hipMemsetAsync(kvb4, 0, kvZeroBytes, stream);

    // Phase 1: bf16-convert Q/K inputs, then pure-bf16 in-place projections.
    cvt_k<<<2048, 256, 0, stream>>>(inQ, Qb, NROWS * DMODEL / 8);
    transpose_k<<<tg, tb, 0, stream>>>(WQ, Wt);
    gemm128<<<ggFull, 256, 0, stream>>>(Qb, Wt, Qb, 1, Qsum);     // in-place
    cvt_k<<<2048, 256, 0, stream>>>(inK, KCb, NROWS * DMODEL / 8);
    transpose_k<<<tg, tb, 0, stream>>>(WK, Wt);
    gemm128<<<ggFull, 256, 0, stream>>>(KCb, Wt, KCb, 1, Ksum);   // in-place
    transpose_k<<<tg, tb, 0, stream>>>(WV, Wt);   // WVt stays through P2

    // Stats: vectorized dots1(+colsum2), dots2, softmax — all 4 batches per launch
    dots1_k<<<dim3(NHEAD, 16, 4), 256, 0, stream>>>(Qb, KCb, Qsum, Ksum, si, QsI, KsO);
    dots_k<<<dim3(NHEAD, 16, 4), 256, 0, stream>>>(Qb, KCb, KsO, QsI, soCsk, css);
    softmax_k<<<dim3(NHEAD, 4), 256, 0, stream>>>(css, css);

    // Phase 2a: per-batch V conversion + in-place projection + kv
    for (int b = 0; b < 4; ++b) {
        size_t rowOff = (size_t)b * BATSTRIDE;
        size_t statOff = (size_t)b * NHEAD * S_LEN;
        cvt_k<<<1024, 256, 0, stream>>>(inV + rowOff, Vb, BROWS * DMODEL / 8);
        gemm64<<<ggB64, 256, 0, stream>>>(Vb, Wt, Vb, 0);         // in-place
        kv_k<<<dim3(NHEAD, KV_SPLIT), 256, 0, stream>>>(KCb + rowOff, Vb,
                                                        css + statOff,
                                                        kvb4 + (size_t)b * NHEAD * 4096);
    }
    // Phase 2b: batched ctx (all b): reads Qb/kvb4/si/csk, overwrites dead K_b
    ctx_k<<<dim3(NHEAD, KV_SPLIT, 4), 256, 0, stream>>>(Qb, kvb4, si, soCsk, KCb);

    // Phase 3: ONE z-batched gemm128z (ctx @ WF^T), then ln in order 3,2,1,0.
    // O placement: z=0->Vb (dead), z>=1 -> Qb+(z-1)*8MB (Q dead after ctx).
    transpose_k<<<tg, tb, 0, stream>>>(WF, Wt);   // WVt dead now
    gemm128z<<<ggP3, 256, 0, stream>>>(KCb, Wt, Vb, Qb);
    // ln order (clobber-safe, audited R8):
    ln_k<<<BROWS, 256, 0, stream>>>(Qb + 2 * BATSTRIDE, inQ + 3 * BATSTRIDE,
                                    gamma, beta, outf + 3 * BATSTRIDE);
    ln_k<<<BROWS, 256, 0, stream>>>(Qb + 1 * BATSTRIDE, inQ + 2 * BATSTRIDE,
                                    gamma, beta, outf + 2 * BATSTRIDE);
    ln_k<<<BROWS, 256, 0, stream>>>(Qb, inQ + 1 * BATSTRIDE,
                                    gamma, beta, outf + 1 * BATSTRIDE);
    ln_k<<<BROWS, 256, 0, stream>>>(Vb, inQ, gamma, beta, outf);
}

// Round 12
// 667.639 us; speedup vs baseline: 1.4146x; 1.2505x over previous
//
#include <hip/hip_runtime.h>
#include <hip/hip_bf16.h>

// FlowAttention: B=4 S=4096 D=1024 H=16 dk=dv=64. Inputs/outputs fp32.
// Round-17: kv_k atomic-coalescing remap. R11 counters: kv_k = 62us x4 with
// WRITE_SIZE = exactly 64MB/dispatch = 2M atomics x 32B sectors (scattered map:
// lane stride 128 floats). New thread map: v = t&63 (lane), k-group = wave*16.
//  - atomics for fixed k are 64 contiguous floats per wave -> ~8x less traffic.
//  - Kw LDS reads become wave-uniform broadcasts (free); V reads 2B/lane (free).
//  - same FMA count, same staging, same f32 accumulation.
// Everything else unchanged from R11 (passed at 835us).
#define S_LEN 4096
#define DMODEL 1024
#define NHEAD 16
#define NROWS 16384      // B*S
#define BROWS 4096       // rows per batch
#define KV_SPLIT 32
#define BATSTRIDE 4194304ull   // elements per batch slice (4096*1024)

typedef __bf16 bf16x8 __attribute__((ext_vector_type(8)));
typedef float  f32x4  __attribute__((ext_vector_type(4)));

__device__ __forceinline__ float b2f(ushort u) {
    union { uint i; float f; } c; c.i = ((uint)u) << 16; return c.f;
}
__device__ __forceinline__ float blo(uint u) {
    union { uint i; float f; } c; c.i = u << 16; return c.f;
}
__device__ __forceinline__ float bhi(uint u) {
    union { uint i; float f; } c; c.i = u & 0xFFFF0000u; return c.f;
}
__device__ __forceinline__ ushort f2b(float f) {
    union { uint i; float f; } c; c.f = f;
    uint r = c.i + 0x7FFF + ((c.i >> 16) & 1);   // round-to-nearest-even
    return (ushort)(r >> 16);
}
__device__ __forceinline__ float sigmoidf_(float x) {
    return 1.f / (1.f + __expf(-x));
}

// async 16B global->LDS DMA. Dest must be thread-linear (base + tid*16).
__device__ __forceinline__ void gld_lds16(void* lds, const void* g) {
    __builtin_amdgcn_global_load_lds(
        (const __attribute__((address_space(1))) uint*)g,
        (__attribute__((address_space(3))) uint*)lds, 16, 0, 0);
}

// ---------------- fp32 -> bf16 (RNE), vectorized grid-stride --------------------
__global__ void cvt_k(const float* __restrict__ in, ushort* __restrict__ out, int n8) {
    int idx = blockIdx.x * blockDim.x + threadIdx.x;
    int stride = gridDim.x * blockDim.x;
    for (int i = idx; i < n8; i += stride) {
        float4 a = *(const float4*)(in + (size_t)i * 8);
        float4 b = *(const float4*)(in + (size_t)i * 8 + 4);
        union { ushort u[8]; uint4 v; } o;
        o.u[0] = f2b(a.x); o.u[1] = f2b(a.y); o.u[2] = f2b(a.z); o.u[3] = f2b(a.w);
        o.u[4] = f2b(b.x); o.u[5] = f2b(b.y); o.u[6] = f2b(b.z); o.u[7] = f2b(b.w);
        *(uint4*)(out + (size_t)i * 8) = o.v;
    }
}

// ---------------- transpose 1024x1024: out[n][k] = bf16(in[k][n]), in fp32 ------
__global__ void transpose_k(const float* __restrict__ in, ushort* __restrict__ out) {
    __shared__ ushort tile[32][33];
    int x = blockIdx.x * 32 + threadIdx.x;
    int y0 = blockIdx.y * 32;
    for (int i = threadIdx.y; i < 32; i += 8)
        tile[i][threadIdx.x] = f2b(in[(size_t)(y0 + i) * DMODEL + x]);
    __syncthreads();
    int xo = blockIdx.y * 32 + threadIdx.x;
    int yo0 = blockIdx.x * 32;
    for (int i = threadIdx.y; i < 32; i += 8)
        out[(size_t)(yo0 + i) * DMODEL + xo] = tile[threadIdx.x][i];
}

// ---------------- MFMA GEMM 128x128, bf16 A (in-place capable) ------------------
__global__ __launch_bounds__(256) void gemm128(const ushort* __restrict__ A,
                                               const ushort* __restrict__ Bt,
                                               ushort* __restrict__ C, int act,
                                               float* __restrict__ csum) {
    __shared__ __align__(16) char smem[32768];
    char* smA = smem + 16384;

    int nwg = (int)(gridDim.x * gridDim.y);
    int bid = (int)(blockIdx.y * gridDim.x + blockIdx.x);
    int lid = (bid & 7) * (nwg >> 3) + (bid >> 3);
    int n0 = (lid & 7) * 128;                     // gridDim.x == 8
    int m0 = (lid >> 3) * 128;

    int t = threadIdx.x;
    int lane = t & 63, wave = t >> 6;
    int wm = (wave >> 1) * 64, wn = (wave & 1) * 64;
    int fr = lane & 15;            // frag row (A) / col (B)
    int kq = (lane >> 4) * 8;      // k offset within 32-step

    int ldsOff[4], rowOf[4], bcB[4];
    #pragma unroll
    for (int r = 0; r < 4; ++r) {
        int o = t * 16 + r * 4096;
        int row = o >> 7;
        ldsOff[r] = o;
        rowOf[r] = row;
        bcB[r] = (o & 127) ^ ((row & 7) << 4);
    }

    f32x4 acc[4][4];
    #pragma unroll
    for (int i = 0; i < 4; ++i)
        #pragma unroll
        for (int j = 0; j < 4; ++j) acc[i][j] = (f32x4){0.f, 0.f, 0.f, 0.f};

    for (int k0 = 0; k0 < DMODEL; k0 += 64) {
        __syncthreads();
        #pragma unroll
        for (int r = 0; r < 4; ++r)
            gld_lds16(smem + ldsOff[r],
                      Bt + (size_t)(n0 + rowOf[r]) * DMODEL + k0 + (bcB[r] >> 1));
        #pragma unroll
        for (int r = 0; r < 4; ++r)
            gld_lds16(smA + ldsOff[r],
                      A + (size_t)(m0 + rowOf[r]) * DMODEL + k0 + (bcB[r] >> 1));
        __syncthreads();

        #pragma unroll
        for (int h = 0; h < 2; ++h) {
            bf16x8 av[4], bv[4];
            #pragma unroll
            for (int i = 0; i < 4; ++i) {
                int row = wm + i * 16 + fr;
                int k = h * 32 + kq;
                int o = ((row << 7) + (k << 1)) ^ ((row & 7) << 4);
                av[i] = *(const bf16x8*)(smA + o);
            }
            #pragma unroll
            for (int j = 0; j < 4; ++j) {
                int nrow = wn + j * 16 + fr;
                int k = h * 32 + kq;
                int o = ((nrow << 7) + (k << 1)) ^ ((nrow & 7) << 4);
                bv[j] = *(const bf16x8*)(smem + o);
            }
            #pragma unroll
            for (int i = 0; i < 4; ++i)
                #pragma unroll
                for (int j = 0; j < 4; ++j)
                    acc[i][j] = __builtin_amdgcn_mfma_f32_16x16x32_bf16(av[i], bv[j], acc[i][j], 0, 0, 0);
        }
    }

    int rbase = (lane >> 4) * 4;
    int cix = lane & 15;
    float colacc[4] = {0.f, 0.f, 0.f, 0.f};
    #pragma unroll
    for (int i = 0; i < 4; ++i)
        #pragma unroll
        for (int j = 0; j < 4; ++j) {
            int col = n0 + wn + j * 16 + cix;
            #pragma unroll
            for (int r = 0; r < 4; ++r) {
                int row = m0 + wm + i * 16 + rbase + r;
                float v = acc[i][j][r];
                if (act) v = sigmoidf_(v);
                ushort ub = f2b(v);
                C[(size_t)row * DMODEL + col] = ub;
                if (csum) colacc[j] += b2f(ub);
            }
        }
    if (csum) {
        __syncthreads();
        float* cred = (float*)smem;     // [2][128]
        cred[t] = 0.f;
        __syncthreads();
        #pragma unroll
        for (int j = 0; j < 4; ++j) {
            float s = colacc[j];
            s += __shfl_xor(s, 16);
            s += __shfl_xor(s, 32);
            if (lane < 16) cred[(wm >> 6) * 128 + wn + j * 16 + lane] = s;
        }
        __syncthreads();
        if (t < 128) {
            float tot = cred[t] + cred[128 + t];
            int col = n0 + t;
            int b = m0 >> 12;
            atomicAdd(&csum[((size_t)b * NHEAD + (col >> 6)) * 64 + (col & 63)], tot);
        }
    }
}

// ---------------- MFMA GEMM 128x128, bf16 A, z-batched (P3) ---------------------
__global__ __launch_bounds__(256) void gemm128z(const ushort* __restrict__ A,
                                                const ushort* __restrict__ Bt,
                                                ushort* __restrict__ C0,
                                                ushort* __restrict__ C1) {
    __shared__ __align__(16) char smem[32768];
    char* smA = smem + 16384;

    int z = (int)blockIdx.z;
    const ushort* Ab = A + (size_t)z * BATSTRIDE;
    ushort* C = z ? C1 + (size_t)(z - 1) * BATSTRIDE : C0;

    int nwg = (int)(gridDim.x * gridDim.y);       // 256 per slice
    int bid = (int)(blockIdx.y * gridDim.x + blockIdx.x);
    int lid = (bid & 7) * (nwg >> 3) + (bid >> 3);
    int n0 = (lid & 7) * 128;
    int m0 = (lid >> 3) * 128;                    // [0, 4096)

    int t = threadIdx.x;
    int lane = t & 63, wave = t >> 6;
    int wm = (wave >> 1) * 64, wn = (wave & 1) * 64;
    int fr = lane & 15;
    int kq = (lane >> 4) * 8;

    int ldsOff[4], rowOf[4], bcB[4];
    #pragma unroll
    for (int r = 0; r < 4; ++r) {
        int o = t * 16 + r * 4096;
        int row = o >> 7;
        ldsOff[r] = o;
        rowOf[r] = row;
        bcB[r] = (o & 127) ^ ((row & 7) << 4);
    }

    f32x4 acc[4][4];
    #pragma unroll
    for (int i = 0; i < 4; ++i)
        #pragma unroll
        for (int j = 0; j < 4; ++j) acc[i][j] = (f32x4){0.f, 0.f, 0.f, 0.f};

    for (int k0 = 0; k0 < DMODEL; k0 += 64) {
        __syncthreads();
        #pragma unroll
        for (int r = 0; r < 4; ++r)
            gld_lds16(smem + ldsOff[r],
                      Bt + (size_t)(n0 + rowOf[r]) * DMODEL + k0 + (bcB[r] >> 1));
        #pragma unroll
        for (int r = 0; r < 4; ++r)
            gld_lds16(smA + ldsOff[r],
                      Ab + (size_t)(m0 + rowOf[r]) * DMODEL + k0 + (bcB[r] >> 1));
        __syncthreads();

        #pragma unroll
        for (int h = 0; h < 2; ++h) {
            bf16x8 av[4], bv[4];
            #pragma unroll
            for (int i = 0; i < 4; ++i) {
                int row = wm + i * 16 + fr;
                int k = h * 32 + kq;
                int o = ((row << 7) + (k << 1)) ^ ((row & 7) << 4);
                av[i] = *(const bf16x8*)(smA + o);
            }
            #pragma unroll
            for (int j = 0; j < 4; ++j) {
                int nrow = wn + j * 16 + fr;
                int k = h * 32 + kq;
                int o = ((nrow << 7) + (k << 1)) ^ ((nrow & 7) << 4);
                bv[j] = *(const bf16x8*)(smem + o);
            }
            #pragma unroll
            for (int i = 0; i < 4; ++i)
                #pragma unroll
                for (int j = 0; j < 4; ++j)
                    acc[i][j] = __builtin_amdgcn_mfma_f32_16x16x32_bf16(av[i], bv[j], acc[i][j], 0, 0, 0);
        }
    }

    int rbase = (lane >> 4) * 4;
    int cix = lane & 15;
    #pragma unroll
    for (int i = 0; i < 4; ++i)
        #pragma unroll
        for (int j = 0; j < 4; ++j) {
            int col = n0 + wn + j * 16 + cix;
            #pragma unroll
            for (int r = 0; r < 4; ++r) {
                int row = m0 + wm + i * 16 + rbase + r;
                C[(size_t)row * DMODEL + col] = f2b(acc[i][j][r]);
            }
        }
}

// ---------------- MFMA GEMM 64x64, bf16 A (per-batch V-proj, in-place) ----------
__global__ __launch_bounds__(256) void gemm64(const ushort* __restrict__ A,
                                              const ushort* __restrict__ Bt,
                                              ushort* __restrict__ C, int act) {
    __shared__ __align__(16) char smem[16384];
    char* smA = smem + 8192;

    int nwg = (int)(gridDim.x * gridDim.y);                  // 1024
    int bid = (int)(blockIdx.y * gridDim.x + blockIdx.x);
    int lid = (bid & 7) * (nwg >> 3) + (bid >> 3);
    int n0 = (lid & 15) * 64;                                // gridDim.x == 16
    int m0 = (lid >> 4) * 64;

    int t = threadIdx.x;
    int lane = t & 63, wave = t >> 6;
    int wm = (wave >> 1) * 32, wn = (wave & 1) * 32;
    int fr = lane & 15;
    int kq = (lane >> 4) * 8;

    f32x4 acc[2][2];
    #pragma unroll
    for (int i = 0; i < 2; ++i)
        #pragma unroll
        for (int j = 0; j < 2; ++j) acc[i][j] = (f32x4){0.f, 0.f, 0.f, 0.f};

    for (int k0 = 0; k0 < DMODEL; k0 += 64) {
        __syncthreads();
        #pragma unroll
        for (int r = 0; r < 2; ++r) {
            int o = t * 16 + r * 4096;
            int row = o >> 7;
            int cb = (o & 127) ^ ((row & 7) << 4);
            gld_lds16(smem + o, Bt + (size_t)(n0 + row) * DMODEL + k0 + (cb >> 1));
        }
        #pragma unroll
        for (int r = 0; r < 2; ++r) {
            int o = t * 16 + r * 4096;
            int row = o >> 7;
            int cb = (o & 127) ^ ((row & 7) << 4);
            gld_lds16(smA + o, A + (size_t)(m0 + row) * DMODEL + k0 + (cb >> 1));
        }
        __syncthreads();   // vmcnt(0) drain

        #pragma unroll
        for (int h = 0; h < 2; ++h) {
            bf16x8 av[2], bv[2];
            #pragma unroll
            for (int i = 0; i < 2; ++i) {
                int row = wm + i * 16 + fr;
                int k = h * 32 + kq;
                int o = ((row << 7) + (k << 1)) ^ ((row & 7) << 4);
                av[i] = *(const bf16x8*)(smA + o);
            }
            #pragma unroll
            for (int j = 0; j < 2; ++j) {
                int nrow = wn + j * 16 + fr;
                int k = h * 32 + kq;
                int o = ((nrow << 7) + (k << 1)) ^ ((nrow & 7) << 4);
                bv[j] = *(const bf16x8*)(smem + o);
            }
            #pragma unroll
            for (int i = 0; i < 2; ++i)
                #pragma unroll
                for (int j = 0; j < 2; ++j)
                    acc[i][j] = __builtin_amdgcn_mfma_f32_16x16x32_bf16(av[i], bv[j], acc[i][j], 0, 0, 0);
        }
    }

    int rbase = (lane >> 4) * 4;
    int cix = lane & 15;
    #pragma unroll
    for (int i = 0; i < 2; ++i)
        #pragma unroll
        for (int j = 0; j < 2; ++j) {
            int col = n0 + wn + j * 16 + cix;
            #pragma unroll
            for (int r = 0; r < 4; ++r) {
                int row = m0 + wm + i * 16 + rbase + r;
                float v = acc[i][j][r];
                if (act) v = sigmoidf_(v);
                C[(size_t)row * DMODEL + col] = f2b(v);
            }
        }
}

// ---- fused dots1 + weighted colsum2, vectorized (8 lanes per s) ----
__global__ void dots1_k(const ushort* __restrict__ Q, const ushort* __restrict__ K,
                        const float* __restrict__ Qsum, const float* __restrict__ Ksum,
                        float* __restrict__ si_out, float* __restrict__ qsi,
                        float* __restrict__ kso) {
    int h = blockIdx.x, b = blockIdx.z;
    int t = threadIdx.x;
    int lane = t & 63, wv = t >> 6;
    int g = lane >> 3, e = lane & 7;
    size_t bh = (size_t)b * NHEAD + h;
    const ushort* qp = Q + (size_t)b * BATSTRIDE + h * 64 + e * 8;
    const ushort* kp = K + (size_t)b * BATSTRIDE + h * 64 + e * 8;
    float4 vq0 = *(const float4*)&Ksum[bh * 64 + e * 8];
    float4 vq1 = *(const float4*)&Ksum[bh * 64 + e * 8 + 4];
    float4 vk0 = *(const float4*)&Qsum[bh * 64 + e * 8];
    float4 vk1 = *(const float4*)&Qsum[bh * 64 + e * 8 + 4];
    float* sip = si_out + bh * S_LEN;
    int sBase = blockIdx.y * 256 + wv * 64 + g;
    float aq[8], ak[8];
    #pragma unroll
    for (int j = 0; j < 8; ++j) { aq[j] = 0.f; ak[j] = 0.f; }
    #pragma unroll 2
    for (int i = 0; i < 8; ++i) {
        int s = sBase + i * 8;
        uint4 qr = *(const uint4*)(qp + (size_t)s * DMODEL);
        uint4 kr = *(const uint4*)(kp + (size_t)s * DMODEL);
        float qf[8] = { blo(qr.x), bhi(qr.x), blo(qr.y), bhi(qr.y),
                        blo(qr.z), bhi(qr.z), blo(qr.w), bhi(qr.w) };
        float kf[8] = { blo(kr.x), bhi(kr.x), blo(kr.y), bhi(kr.y),
                        blo(kr.z), bhi(kr.z), blo(kr.w), bhi(kr.w) };
        float dq = qf[0] * vq0.x + qf[1] * vq0.y + qf[2] * vq0.z + qf[3] * vq0.w
                 + qf[4] * vq1.x + qf[5] * vq1.y + qf[6] * vq1.z + qf[7] * vq1.w;
        float dk = kf[0] * vk0.x + kf[1] * vk0.y + kf[2] * vk0.z + kf[3] * vk0.w
                 + kf[4] * vk1.x + kf[5] * vk1.y + kf[6] * vk1.z + kf[7] * vk1.w;
        dq += __shfl_xor(dq, 1); dq += __shfl_xor(dq, 2); dq += __shfl_xor(dq, 4);
        dk += __shfl_xor(dk, 1); dk += __shfl_xor(dk, 2); dk += __shfl_xor(dk, 4);
        float si_ = 1.f / dq, so_ = 1.f / dk;
        if (e == 0) sip[s] = si_;
        #pragma unroll
        for (int j = 0; j < 8; ++j) {
            aq[j] += qf[j] * si_;
            ak[j] += kf[j] * so_;
        }
    }
    #pragma unroll
    for (int j = 0; j < 8; ++j) {
        float v = aq[j];
        v += __shfl_xor(v, 8); v += __shfl_xor(v, 16); v += __shfl_xor(v, 32);
        float u = ak[j];
        u += __shfl_xor(u, 8); u += __shfl_xor(u, 16); u += __shfl_xor(u, 32);
        if (g == 0) {
            atomicAdd(&qsi[bh * 64 + e * 8 + j], v);
            atomicAdd(&kso[bh * 64 + e * 8 + j], u);
        }
    }
}

// ---- dots2 vectorized: csk[s]=Q[s]·vq, css[s]=K[s]·vk ----
__global__ void dots_k(const ushort* __restrict__ Q, const ushort* __restrict__ K,
                       const float* __restrict__ vq, const float* __restrict__ vk,
                       float* __restrict__ outq, float* __restrict__ outk) {
    int h = blockIdx.x, b = blockIdx.z;
    int t = threadIdx.x;
    int lane = t & 63, wv = t >> 6;
    int g = lane >> 3, e = lane & 7;
    size_t bh = (size_t)b * NHEAD + h;
    const ushort* qp = Q + (size_t)b * BATSTRIDE + h * 64 + e * 8;
    const ushort* kp = K + (size_t)b * BATSTRIDE + h * 64 + e * 8;
    float4 vq0 = *(const float4*)&vq[bh * 64 + e * 8];
    float4 vq1 = *(const float4*)&vq[bh * 64 + e * 8 + 4];
    float4 vk0 = *(const float4*)&vk[bh * 64 + e * 8];
    float4 vk1 = *(const float4*)&vk[bh * 64 + e * 8 + 4];
    float* oq = outq + bh * S_LEN;
    float* ok = outk + bh * S_LEN;
    int sBase = blockIdx.y * 256 + wv * 64 + g;
    #pragma unroll 2
    for (int i = 0; i < 8; ++i) {
        int s = sBase + i * 8;
        uint4 qr = *(const uint4*)(qp + (size_t)s * DMODEL);
        uint4 kr = *(const uint4*)(kp + (size_t)s * DMODEL);
        float dq = blo(qr.x) * vq0.x + bhi(qr.x) * vq0.y + blo(qr.y) * vq0.z + bhi(qr.y) * vq0.w
                 + blo(qr.z) * vq1.x + bhi(qr.z) * vq1.y + blo(qr.w) * vq1.z + bhi(qr.w) * vq1.w;
        float dk = blo(kr.x) * vk0.x + bhi(kr.x) * vk0.y + blo(kr.y) * vk0.z + bhi(kr.y) * vk0.w
                 + blo(kr.z) * vk1.x + bhi(kr.z) * vk1.y + blo(kr.w) * vk1.z + bhi(kr.w) * vk1.w;
        dq += __shfl_xor(dq, 1); dq += __shfl_xor(dq, 2); dq += __shfl_xor(dq, 4);
        dk += __shfl_xor(dk, 1); dk += __shfl_xor(dk, 2); dk += __shfl_xor(dk, 4);
        if (e == 0) {
            oq[s] = dq;
            ok[s] = dk;
        }
    }
}

// ---- softmax over S per head, batched over b (y); safe in-place ----
__global__ void softmax_k(const float* x, float* w) {
    int h = blockIdx.x;
    int b = blockIdx.y;
    const float* xp = x + ((size_t)b * NHEAD + h) * S_LEN;
    float* wp = w + ((size_t)b * NHEAD + h) * S_LEN;
    float loc[16];
    float mx = -1e30f;
    #pragma unroll
    for (int i = 0; i < 16; ++i) { loc[i] = xp[threadIdx.x + i * 256]; mx = fmaxf(mx, loc[i]); }
    __shared__ float red[256];
    red[threadIdx.x] = mx; __syncthreads();
    for (int st = 128; st; st >>= 1) {
        if (threadIdx.x < st) red[threadIdx.x] = fmaxf(red[threadIdx.x], red[threadIdx.x + st]);
        __syncthreads();
    }
    mx = red[0]; __syncthreads();
    float sm = 0.f;
    #pragma unroll
    for (int i = 0; i < 16; ++i) { loc[i] = __expf(loc[i] - mx); sm += loc[i]; }
    red[threadIdx.x] = sm; __syncthreads();
    for (int st = 128; st; st >>= 1) {
        if (threadIdx.x < st) red[threadIdx.x] += red[threadIdx.x + st];
        __syncthreads();
    }
    float inv = 1.f / red[0];
    #pragma unroll
    for (int i = 0; i < 16; ++i)
        wp[threadIdx.x + i * 256] = loc[i] * inv;
}

// ---- kv[h,k,v] = sum_s (K[s,k]*w[h,s]) * V[s,v], one batch ----
// Thread map (atomic-coalescing): v = t&63 (lane), k-group = (t>>6)*16 (wave).
// Kw LDS reads are wave-uniform broadcasts; V reads 2B/lane stride-1.
// Atomics: for fixed k, wave covers kvp[k*64 + 0..63] contiguous (coalesced).
__global__ __launch_bounds__(256) void kv_k(const ushort* __restrict__ K,
                                            const ushort* __restrict__ V,
                                            const float* __restrict__ w,
                                            float* __restrict__ kv) {
    int bid = (int)(blockIdx.y * gridDim.x + blockIdx.x);   // gridDim = (16, 32)
    int lid = (bid & 7) * 64 + (bid >> 3);                  // [0,512) bijective
    int h = lid & 15;
    int sy = lid >> 4;                                      // [0,32)
    __shared__ __align__(16) float  KwS[64 * 64];           // [s][k] f32, swizzled
    __shared__ __align__(16) ushort Vt[64 * 64];            // [s][v] bf16, linear
    int t = threadIdx.x;
    int v = t & 63;                 // lane = v
    int k0g = (t >> 6) * 16;        // wave covers 16 consecutive k
    float acc[16];
    #pragma unroll
    for (int j = 0; j < 16; ++j) acc[j] = 0.f;
    int sl_s = t >> 2, q = t & 3;   // staging: row, quarter
    int sBase = sy * (S_LEN / KV_SPLIT);                    // 128 rows per block
    for (int t0 = 0; t0 < S_LEN / KV_SPLIT; t0 += 64) {
        __syncthreads();
        // V tile: 8KB linear, 2 DMA rounds
        #pragma unroll
        for (int r = 0; r < 2; ++r) {
            int o = t * 16 + r * 4096;
            int row = o >> 7;
            gld_lds16((char*)Vt + o,
                      V + (size_t)(sBase + t0 + row) * DMODEL + h * 64 + ((o & 127) >> 1));
        }
        // K tile: reg-staged f32 * w, swizzled
        {
            int s = sBase + t0 + sl_s;
            float ws = w[(size_t)h * S_LEN + s];
            const ushort* kp = K + (size_t)s * DMODEL + h * 64 + q * 16;
            uint4 ka = *(const uint4*)kp;
            uint4 kb = *(const uint4*)(kp + 8);
            int swz = (sl_s & 7) << 4;
            char* base = (char*)KwS + sl_s * 256;
            f32x4 c0 = { blo(ka.x) * ws, bhi(ka.x) * ws, blo(ka.y) * ws, bhi(ka.y) * ws };
            f32x4 c1 = { blo(ka.z) * ws, bhi(ka.z) * ws, blo(ka.w) * ws, bhi(ka.w) * ws };
            f32x4 c2 = { blo(kb.x) * ws, bhi(kb.x) * ws, blo(kb.y) * ws, bhi(kb.y) * ws };
            f32x4 c3 = { blo(kb.z) * ws, bhi(kb.z) * ws, blo(kb.w) * ws, bhi(kb.w) * ws };
            *(f32x4*)(base + ((q * 64 +  0) ^ swz)) = c0;
            *(f32x4*)(base + ((q * 64 + 16) ^ swz)) = c1;
            *(f32x4*)(base + ((q * 64 + 32) ^ swz)) = c2;
            *(f32x4*)(base + ((q * 64 + 48) ^ swz)) = c3;
        }
        __syncthreads();
        #pragma unroll 2
        for (int sl = 0; sl < 64; ++sl) {
            int swz = (sl & 7) << 4;
            const char* krow = (const char*)KwS + sl * 256;
            // 16 k values, wave-uniform (broadcast reads)
            f32x4 k0 = *(const f32x4*)(krow + (((k0g +  0) * 4) ^ swz));
            f32x4 k1 = *(const f32x4*)(krow + (((k0g +  4) * 4) ^ swz));
            f32x4 k2 = *(const f32x4*)(krow + (((k0g +  8) * 4) ^ swz));
            f32x4 k3 = *(const f32x4*)(krow + (((k0g + 12) * 4) ^ swz));
            float vf = b2f(Vt[sl * 64 + v]);
            acc[ 0] += k0[0] * vf; acc[ 1] += k0[1] * vf;
            acc[ 2] += k0[2] * vf; acc[ 3] += k0[3] * vf;
            acc[ 4] += k1[0] * vf; acc[ 5] += k1[1] * vf;
            acc[ 6] += k1[2] * vf; acc[ 7] += k1[3] * vf;
            acc[ 8] += k2[0] * vf; acc[ 9] += k2[1] * vf;
            acc[10] += k2[2] * vf; acc[11] += k2[3] * vf;
            acc[12] += k3[0] * vf; acc[13] += k3[1] * vf;
            acc[14] += k3[2] * vf; acc[15] += k3[3] * vf;
        }
    }
    float* kvp = kv + (size_t)h * 4096;
    #pragma unroll
    for (int j = 0; j < 16; ++j)
        atomicAdd(&kvp[(k0g + j) * 64 + v], acc[j]);   // wave: 64 contiguous floats
}

// ---- ctx[s,h*64+v] = sig(csink)*si*sum_k Q[s,k]*kv[k,v]; batched over b (z) ----
__global__ __launch_bounds__(256) void ctx_k(const ushort* __restrict__ Qall,
                                             const float* __restrict__ kv4,
                                             const float* __restrict__ siAll,
                                             const float* __restrict__ cskAll,
                                             ushort* __restrict__ ctxAll) {
    int b = (int)blockIdx.z;
    const ushort* Q = Qall + (size_t)b * BATSTRIDE;
    const float* kv = kv4 + (size_t)b * NHEAD * 4096;
    const float* si = siAll + (size_t)b * NHEAD * S_LEN;
    const float* csink = cskAll + (size_t)b * NHEAD * S_LEN;
    ushort* ctx = ctxAll + (size_t)b * BATSTRIDE;

    int bid = (int)(blockIdx.y * gridDim.x + blockIdx.x);   // gridDim = (16, 32)
    int lid = (bid & 7) * 64 + (bid >> 3);                  // [0,512) bijective
    int h = lid & 15;
    int sBlock = (lid >> 4) * 128;
    __shared__ __align__(16) float  kvf[64 * 64];   // [k][v] linear
    __shared__ __align__(16) ushort Qt[64 * 64];    // [s][k] source-preswizzled
    int t = threadIdx.x;
    {
        const float* kp = kv + (size_t)h * 4096;
        #pragma unroll
        for (int i = 0; i < 4; ++i) {
            int idx = t * 4 + i * 1024;
            *(f32x4*)&kvf[idx] = *(const f32x4*)&kp[idx];
        }
    }
    int spair = t >> 3;
    int v0 = (t & 7) * 8;
    for (int tile = 0; tile < 2; ++tile) {
        __syncthreads();
        int sT = sBlock + tile * 64;
        #pragma unroll
        for (int r = 0; r < 2; ++r) {
            int o = t * 16 + r * 4096;
            int row = o >> 7;
            int cb = (o & 127) ^ ((row & 7) << 4);
            gld_lds16((char*)Qt + o, Q + (size_t)(sT + row) * DMODEL + h * 64 + (cb >> 1));
        }
        __syncthreads();
        int s0 = spair * 2, s1 = s0 + 1;
        int swz0 = (s0 & 7) << 4, swz1 = (s1 & 7) << 4;
        float acc0[8], acc1[8];
        #pragma unroll
        for (int j = 0; j < 8; ++j) { acc0[j] = 0.f; acc1[j] = 0.f; }
        #pragma unroll 4
        for (int k = 0; k < 64; k += 4) {
            union { ushort4 v; ushort u[4]; } qa, qb;
            qa.v = *(const ushort4*)((const char*)Qt + s0 * 128 + ((k * 2) ^ swz0));
            qb.v = *(const ushort4*)((const char*)Qt + s1 * 128 + ((k * 2) ^ swz1));
            const char* rbase = (const char*)kvf + k * 256 + v0 * 4;
            #pragma unroll
            for (int kk2 = 0; kk2 < 4; ++kk2) {
                f32x4 r0 = *(const f32x4*)(rbase + kk2 * 256);
                f32x4 r1 = *(const f32x4*)(rbase + kk2 * 256 + 16);
                float qaf = b2f(qa.u[kk2]);
                float qbf = b2f(qb.u[kk2]);
                #pragma unroll
                for (int j = 0; j < 4; ++j) {
                    acc0[j]     += qaf * r0[j];
                    acc0[4 + j] += qaf * r1[j];
                    acc1[j]     += qbf * r0[j];
                    acc1[4 + j] += qbf * r1[j];
                }
            }
        }
        int gs0 = sT + s0, gs1 = sT + s1;
        float sc0 = si[(size_t)h * S_LEN + gs0] * sigmoidf_(csink[(size_t)h * S_LEN + gs0]);
        float sc1 = si[(size_t)h * S_LEN + gs1] * sigmoidf_(csink[(size_t)h * S_LEN + gs1]);
        union { ushort u[8]; uint4 v; } o0, o1;
        #pragma unroll
        for (int j = 0; j < 8; ++j) {
            o0.u[j] = f2b(acc0[j] * sc0);
            o1.u[j] = f2b(acc1[j] * sc1);
        }
        *(uint4*)(ctx + (size_t)gs0 * DMODEL + h * 64 + v0) = o0.v;
        *(uint4*)(ctx + (size_t)gs1 * DMODEL + h * 64 + v0) = o1.v;
    }
}

// ---- LayerNorm(y_bf16 + residual_f32) * gamma + beta -> fp32 out (per-row) ----
__global__ void ln_k(const ushort* __restrict__ y, const float* __restrict__ res,
                     const float* __restrict__ gamma, const float* __restrict__ beta,
                     float* __restrict__ out) {
    size_t row = blockIdx.x;
    int d0 = threadIdx.x * 4;
    const ushort* yp = y + row * DMODEL;
    const float* rp = res + row * DMODEL;
    uint2 yv = *(const uint2*)(yp + d0);
    float4 rv = *(const float4*)(rp + d0);
    float x0 = blo(yv.x) + rv.x, x1 = bhi(yv.x) + rv.y;
    float x2 = blo(yv.y) + rv.z, x3 = bhi(yv.y) + rv.w;
    float s = x0 + x1 + x2 + x3;
    float s2 = x0 * x0 + x1 * x1 + x2 * x2 + x3 * x3;
    __shared__ float r1[256], r2[256];
    r1[threadIdx.x] = s; r2[threadIdx.x] = s2;
    __syncthreads();
    for (int st = 128; st; st >>= 1) {
        if (threadIdx.x < st) { r1[threadIdx.x] += r1[threadIdx.x + st]; r2[threadIdx.x] += r2[threadIdx.x + st]; }
        __syncthreads();
    }
    float mean = r1[0] * (1.f / DMODEL);
    float var = r2[0] * (1.f / DMODEL) - mean * mean;
    float rstd = rsqrtf(var + 1e-5f);
    float4 gv = *(const float4*)(gamma + d0);
    float4 bv = *(const float4*)(beta + d0);
    float4 ov;
    ov.x = (x0 - mean) * rstd * gv.x + bv.x;
    ov.y = (x1 - mean) * rstd * gv.y + bv.y;
    ov.z = (x2 - mean) * rstd * gv.z + bv.z;
    ov.w = (x3 - mean) * rstd * gv.w + bv.w;
    *(float4*)(out + row * DMODEL + d0) = ov;
}

extern "C" void kernel_launch(void* const* d_in, const int* in_sizes, int n_in,
                              void* d_out, int out_size, void* d_ws, size_t ws_size,
                              hipStream_t stream) {
    const float* inQ  = (const float*)d_in[0];
    const float* inK  = (const float*)d_in[1];
    const float* inV  = (const float*)d_in[2];
    const float* WQ   = (const float*)d_in[3];
    const float* WK   = (const float*)d_in[4];
    const float* WV   = (const float*)d_in[5];
    const float* WF   = (const float*)d_in[6];
    const float* gamma= (const float*)d_in[7];
    const float* beta = (const float*)d_in[8];
    float* outf = (float*)d_out;

    // d_out scratch: bf16 Q at [0,32MB), bf16 K/ctx at [32,64MB)
    ushort* Qb  = (ushort*)d_out;
    ushort* KCb = (ushort*)d_out + (size_t)NROWS * DMODEL;

    // d_ws layout (peak 14.06MB, proven R8-R11):
    const size_t MB = 1024ull * 1024ull;
    char* w = (char*)d_ws;
    ushort* Vb  = (ushort*)w;                 // [4096][1024] bf16, 8MB; later O_0 slot
    ushort* Wt  = (ushort*)(w + 8 * MB);      // 2MB weight^T slot (WQ->WK->WV->WF)
    float* si    = (float*)(w + 10 * MB);     // [4][16][4096] f32, 1MB
    float* soCsk = si + 4 * NHEAD * S_LEN;    // 1MB: csk (dots2)
    float* css   = soCsk + 4 * NHEAD * S_LEN; // 1MB: css -> smw (softmax in-place)
    float* Qsum  = css + 4 * NHEAD * S_LEN;   // 4 sum buffers x [4][16][64] = 64KB
    float* Ksum  = Qsum + 4 * NHEAD * 64;
    float* QsI   = Ksum + 4 * NHEAD * 64;
    float* KsO   = QsI  + 4 * NHEAD * 64;
    float* kvb4  = KsO  + 4 * NHEAD * 64;     // [4][16][64][64] f32, 1MB (per-batch)
    size_t sumZeroBytes = 4 * 4 * NHEAD * 64 * sizeof(float);       // 64KB
    size_t kvZeroBytes  = 4ull * NHEAD * 4096 * sizeof(float);      // 1MB

    dim3 tb(32, 8);
    dim3 tg(32, 32);
    dim3 ggFull(DMODEL / 128, NROWS / 128);   // (8, 128)
    dim3 ggB64(DMODEL / 64, BROWS / 64);      // (16, 64) per batch
    dim3 ggP3(DMODEL / 128, BROWS / 128, 4);  // (8, 32, 4) batched P3 gemm128z

    // zero Qsum/Ksum/QsI/KsO before gemm epilogue atomics; all kvb once
    hipMemsetAsync(Qsum, 0, sumZeroBytes, stream);
    hipMemsetAsync(kvb4, 0, kvZeroBytes, stream);

    // Phase 1: bf16-convert Q/K inputs, then pure-bf16 in-place projections.
    cvt_k<<<2048, 256, 0, stream>>>(inQ, Qb, NROWS * DMODEL / 8);
    transpose_k<<<tg, tb, 0, stream>>>(WQ, Wt);
    gemm128<<<ggFull, 256, 0, stream>>>(Qb, Wt, Qb, 1, Qsum);     // in-place
    cvt_k<<<2048, 256, 0, stream>>>(inK, KCb, NROWS * DMODEL / 8);
    transpose_k<<<tg, tb, 0, stream>>>(WK, Wt);
    gemm128<<<ggFull, 256, 0, stream>>>(KCb, Wt, KCb, 1, Ksum);   // in-place
    transpose_k<<<tg, tb, 0, stream>>>(WV, Wt);   // WVt stays through P2

    // Stats: vectorized dots1(+colsum2), dots2, softmax — all 4 batches per launch
    dots1_k<<<dim3(NHEAD, 16, 4), 256, 0, stream>>>(Qb, KCb, Qsum, Ksum, si, QsI, KsO);
    dots_k<<<dim3(NHEAD, 16, 4), 256, 0, stream>>>(Qb, KCb, KsO, QsI, soCsk, css);
    softmax_k<<<dim3(NHEAD, 4), 256, 0, stream>>>(css, css);

    // Phase 2a: per-batch V conversion + in-place projection + kv
    for (int b = 0; b < 4; ++b) {
        size_t rowOff = (size_t)b * BATSTRIDE;
        size_t statOff = (size_t)b * NHEAD * S_LEN;
        cvt_k<<<1024, 256, 0, stream>>>(inV + rowOff, Vb, BROWS * DMODEL / 8);
        gemm64<<<ggB64, 256, 0, stream>>>(Vb, Wt, Vb, 0);         // in-place
        kv_k<<<dim3(NHEAD, KV_SPLIT), 256, 0, stream>>>(KCb + rowOff, Vb,
                                                        css + statOff,
                                                        kvb4 + (size_t)b * NHEAD * 4096);
    }
    // Phase 2b: batched ctx (all b): reads Qb/kvb4/si/csk, overwrites dead K_b
    ctx_k<<<dim3(NHEAD, KV_SPLIT, 4), 256, 0, stream>>>(Qb, kvb4, si, soCsk, KCb);

    // Phase 3: ONE z-batched gemm128z (ctx @ WF^T), then ln in order 3,2,1,0.
    // O placement: z=0->Vb (dead), z>=1 -> Qb+(z-1)*8MB (Q dead after ctx).
    transpose_k<<<tg, tb, 0, stream>>>(WF, Wt);   // WVt dead now
    gemm128z<<<ggP3, 256, 0, stream>>>(KCb, Wt, Vb, Qb);
    // ln order (clobber-safe, audited R8):
    ln_k<<<BROWS, 256, 0, stream>>>(Qb + 2 * BATSTRIDE, inQ + 3 * BATSTRIDE,
                                    gamma, beta, outf + 3 * BATSTRIDE);
    ln_k<<<BROWS, 256, 0, stream>>>(Qb + 1 * BATSTRIDE, inQ + 2 * BATSTRIDE,
                                    gamma, beta, outf + 2 * BATSTRIDE);
    ln_k<<<BROWS, 256, 0, stream>>>(Qb, inQ + 1 * BATSTRIDE,
                                    gamma, beta, outf + 1 * BATSTRIDE);
    ln_k<<<BROWS, 256, 0, stream>>>(Vb, inQ, gamma, beta, outf);
}